// Round 3
// baseline (3348.399 us; speedup 1.0000x reference)
//
#include <hip/hip_runtime.h>
#include <hip/hip_bf16.h>
#include <math.h>

typedef unsigned short u16;
using bf16x8 = __attribute__((ext_vector_type(8))) short;
using f32x4  = __attribute__((ext_vector_type(4))) float;

static constexpr int kD = 768;
static constexpr int kH = 12;
static constexpr int kL = 6;
static constexpr int kF = 3072;
static constexpr int kS = 2048;
static constexpr int kB = 4;

__device__ __forceinline__ u16 f2bf(float f) {
    return __bfloat16_as_ushort(__float2bfloat16(f));
}

__device__ __forceinline__ void gload16(const void* g, void* l) {
    auto gp = reinterpret_cast<const __attribute__((address_space(1))) unsigned int*>(
        reinterpret_cast<uintptr_t>(g));
    auto lp = reinterpret_cast<__attribute__((address_space(3))) unsigned int*>(
        reinterpret_cast<uintptr_t>(l));
    __builtin_amdgcn_global_load_lds(gp, lp, 16, 0, 0);
}

// ---------------------------------------------------------------------------
// Embedding + sinusoidal PE; dual-writes f32 residual stream + bf16 copy
// ---------------------------------------------------------------------------
__global__ __launch_bounds__(256) void embed_pe(
    const int* __restrict__ ids, const float* __restrict__ emb,
    float* __restrict__ x, u16* __restrict__ xbf)
{
    const int t = blockIdx.x;
    const int s = t & (kS - 1);
    const int id = ids[t];
#pragma unroll
    for (int j = 0; j < 3; ++j) {
        const int d = threadIdx.x + (j << 8);
        const float i2 = (float)((d >> 1) << 1);
        const float dv = __expf(i2 * (-9.210340371976184f / 768.f));
        const float ang = (float)s * dv;
        const float pe = (d & 1) ? cosf(ang) : sinf(ang);
        const float v = emb[(size_t)id * kD + d] + pe;
        x[(size_t)t * kD + d] = v;
        if (xbf) xbf[(size_t)t * kD + d] = f2bf(v);
    }
}

// mask bias: -1e9 where ids==1 else 0
__global__ __launch_bounds__(256) void mk_mask(const int* __restrict__ ids,
                                               float* __restrict__ mb)
{
    const int i = blockIdx.x * 256 + threadIdx.x;
    if (i < kB * kS) mb[i] = (ids[i] == 1) ? -1e9f : 0.f;
}

// ---------------------------------------------------------------------------
// W[K][N] f32 -> Wt[N][K] bf16 (transpose + convert), 64x64 tiles
// grid: (K/64, N/64)
// ---------------------------------------------------------------------------
__global__ __launch_bounds__(256) void cvt_wT(
    const float* __restrict__ W, u16* __restrict__ Wt, int K, int N)
{
    __shared__ float T[64][68];
    const int k0 = blockIdx.x << 6, n0 = blockIdx.y << 6;
    const int tid = threadIdx.x;
#pragma unroll
    for (int i = 0; i < 4; ++i) {
        const int idx = tid + (i << 8);
        const int kr = idx >> 4;
        const int nc = (idx & 15) << 2;
        const float4 v = *(const float4*)(W + (size_t)(k0 + kr) * N + n0 + nc);
        T[kr][nc] = v.x; T[kr][nc + 1] = v.y; T[kr][nc + 2] = v.z; T[kr][nc + 3] = v.w;
    }
    __syncthreads();
#pragma unroll
    for (int i = 0; i < 4; ++i) {
        const int idx = tid + (i << 8);
        const int nr = idx >> 4;
        const int kc = (idx & 15) << 2;
        ushort4 o;
        o.x = f2bf(T[kc][nr]); o.y = f2bf(T[kc + 1][nr]);
        o.z = f2bf(T[kc + 2][nr]); o.w = f2bf(T[kc + 3][nr]);
        *(ushort4*)(Wt + (size_t)(n0 + nr) * K + k0 + kc) = o;
    }
}

// ---------------------------------------------------------------------------
// bf16 MFMA GEMM: C[M,N] = A[M,K] @ Bt[N,K]^T + bias
// 128x128 tile, BK=32, 256 thr (2x2 waves, 4x4 16x16 frags each).
// global_load_lds staging with pre-swizzled source granule (m173 pattern).
// mode: 0 = f32 out, 1 = bf16 out, 2 = bf16 out + ReLU
// ---------------------------------------------------------------------------
__global__ __launch_bounds__(256) void gemm_bf16(
    const u16* __restrict__ A, const u16* __restrict__ Bt,
    const float* __restrict__ bias, void* __restrict__ Cv,
    int M, int N, int K, int mode)
{
    __shared__ u16 As[4096];
    __shared__ u16 Bs[4096];
    const int tid = threadIdx.x;
    const int l = tid & 63;
    const int lo = l & 15, hi = l >> 4;
    const int w = tid >> 6, wr = w >> 1, wc = w & 1;
    const size_t row0 = (size_t)blockIdx.x * 128;
    const size_t col0 = (size_t)blockIdx.y * 128;

    // staging chunks: tid and tid+256 of 512 x 16B; LDS dest linear,
    // global source granule XOR-swizzled so frag reads are ~2-way.
    const int c0 = tid, c1 = tid + 256;
    const int r0 = c0 >> 2, g0 = (c0 & 3) ^ ((r0 >> 1) & 3);
    const int r1 = c1 >> 2, g1 = (c1 & 3) ^ ((r1 >> 1) & 3);
    const u16* a0 = A  + (row0 + r0) * K + g0 * 8;
    const u16* a1 = A  + (row0 + r1) * K + g1 * 8;
    const u16* b0 = Bt + (col0 + r0) * K + g0 * 8;
    const u16* b1 = Bt + (col0 + r1) * K + g1 * 8;
    u16* sa0 = As + c0 * 8; u16* sa1 = As + c1 * 8;
    u16* sb0 = Bs + c0 * 8; u16* sb1 = Bs + c1 * 8;

    f32x4 acc[4][4];
#pragma unroll
    for (int i = 0; i < 4; ++i)
#pragma unroll
        for (int j = 0; j < 4; ++j)
#pragma unroll
            for (int r = 0; r < 4; ++r) acc[i][j][r] = 0.f;

    int aoff[4], boff[4];
#pragma unroll
    for (int i = 0; i < 4; ++i) {
        const int ra = wr * 64 + i * 16 + lo;
        aoff[i] = ra * 32 + ((hi ^ ((ra >> 1) & 3)) << 3);
        const int rb = wc * 64 + i * 16 + lo;
        boff[i] = rb * 32 + ((hi ^ ((rb >> 1) & 3)) << 3);
    }

    for (int k0 = 0; k0 < K; k0 += 32) {
        __syncthreads();
        gload16(a0 + k0, sa0);
        gload16(a1 + k0, sa1);
        gload16(b0 + k0, sb0);
        gload16(b1 + k0, sb1);
        __syncthreads();
        bf16x8 af[4], bfr[4];
#pragma unroll
        for (int i = 0; i < 4; ++i) af[i] = *(const bf16x8*)&As[aoff[i]];
#pragma unroll
        for (int j = 0; j < 4; ++j) bfr[j] = *(const bf16x8*)&Bs[boff[j]];
#pragma unroll
        for (int i = 0; i < 4; ++i)
#pragma unroll
            for (int j = 0; j < 4; ++j)
                acc[i][j] = __builtin_amdgcn_mfma_f32_16x16x32_bf16(
                    af[i], bfr[j], acc[i][j], 0, 0, 0);
    }

#pragma unroll
    for (int i = 0; i < 4; ++i) {
        const size_t rbase = row0 + wr * 64 + i * 16 + hi * 4;
#pragma unroll
        for (int j = 0; j < 4; ++j) {
            const size_t c = col0 + wc * 64 + j * 16 + lo;
            const float bs = bias[c];
#pragma unroll
            for (int r = 0; r < 4; ++r) {
                float v = acc[i][j][r] + bs;
                if (mode == 2) v = fmaxf(v, 0.f);
                const size_t off = (rbase + r) * (size_t)N + c;
                if (mode == 0) ((float*)Cv)[off] = v;
                else           ((u16*)Cv)[off]  = f2bf(v);
            }
        }
    }
}

// ---------------------------------------------------------------------------
// MFMA flash attention, bf16 in/out. Block: 4 waves, 64 q-rows per block
// (16 per wave); K-tiles of 64 keys staged in swizzled LDS.
// Grid: (S/64, H, B).
// Swizzles (all keep 16B alignment of b128 ops, ~2-way banks):
//   Ks [key][64]: elem = key*64 + (e ^ ((key&7)<<3))
//   Vt [dim][64keys]: elem = d*64 + (key ^ (svz(d)<<3)), svz=(d&7)^((d>>3)&7)
//   Ps [q][64keys] per-wave: elem = q*64 + (key ^ (spz(q)<<3)), spz=(q&7)^((q>>3)<<1)
// ---------------------------------------------------------------------------
__global__ __launch_bounds__(256) void attn_mfma(
    const u16* __restrict__ Q, const u16* __restrict__ Kb,
    const u16* __restrict__ Vb, const float* __restrict__ mb,
    u16* __restrict__ O)
{
    __shared__ u16 Ks[64 * 64];
    __shared__ u16 Vt[64 * 64];
    __shared__ u16 Ps[4 * 16 * 64];
    __shared__ float Mb[kS];

    const int tid = threadIdx.x, l = tid & 63, w = tid >> 6;
    const int lo = l & 15, hi = l >> 4;
    const int h = blockIdx.y, b = blockIdx.z;
    const int q0 = blockIdx.x << 6;

    // stage mask bias row for this batch
#pragma unroll
    for (int i = 0; i < 2; ++i) {
        const int idx = (tid + (i << 8)) << 2;
        *(float4*)&Mb[idx] = *(const float4*)&mb[b * kS + idx];
    }

    // Q fragments: rows q0 + w*16 + lo, two K-steps of 32 dims
    bf16x8 qf[2];
    {
        const u16* qp = Q + ((size_t)(b * kS + q0 + w * 16 + lo)) * kD + h * 64 + hi * 8;
        qf[0] = *(const bf16x8*)qp;
        qf[1] = *(const bf16x8*)(qp + 32);
    }

    f32x4 accO[4];
    float mr[4], lr[4];
#pragma unroll
    for (int n = 0; n < 4; ++n)
#pragma unroll
        for (int r = 0; r < 4; ++r) accO[n][r] = 0.f;
#pragma unroll
    for (int r = 0; r < 4; ++r) { mr[r] = -3.0e38f; lr[r] = 0.f; }

    for (int kt = 0; kt < kS / 64; ++kt) {
        // ---- stage K (row-major swizzled) + V (transposed swizzled) ----
#pragma unroll
        for (int i = 0; i < 2; ++i) {
            const int lin = tid + (i << 8);          // 0..511
            const int key = lin >> 3;
            const int e0 = (lin & 7) << 3;
            const size_t gro = ((size_t)(b * kS + (kt << 6) + key)) * kD + h * 64 + e0;
            union { uint4 u; u16 s[8]; } kv, vv;
            kv.u = *(const uint4*)(Kb + gro);
            vv.u = *(const uint4*)(Vb + gro);
            *(uint4*)&Ks[key * 64 + (e0 ^ ((key & 7) << 3))] = kv.u;
#pragma unroll
            for (int e = 0; e < 8; ++e) {
                const int d = e0 + e;
                const int svz = (d & 7) ^ ((d >> 3) & 7);
                Vt[d * 64 + (key ^ (svz << 3))] = vv.s[e];
            }
        }
        __syncthreads();

        // ---- scores: per wave 16 q-rows x 64 keys ----
        f32x4 sf[4];
#pragma unroll
        for (int j = 0; j < 4; ++j) {
#pragma unroll
            for (int r = 0; r < 4; ++r) sf[j][r] = 0.f;
            const int key = j * 16 + lo;
            const int sw = (key & 7) << 3;
            const bf16x8 k0f = *(const bf16x8*)&Ks[key * 64 + ((hi * 8) ^ sw)];
            const bf16x8 k1f = *(const bf16x8*)&Ks[key * 64 + ((hi * 8 + 32) ^ sw)];
            sf[j] = __builtin_amdgcn_mfma_f32_16x16x32_bf16(qf[0], k0f, sf[j], 0, 0, 0);
            sf[j] = __builtin_amdgcn_mfma_f32_16x16x32_bf16(qf[1], k1f, sf[j], 0, 0, 0);
        }

        // ---- online softmax (rows q = hi*4 + r live in 16-lane groups) ----
        float p[4][4], corr[4], tmax[4], tsum[4];
#pragma unroll
        for (int r = 0; r < 4; ++r) tmax[r] = -3.0e38f;
#pragma unroll
        for (int j = 0; j < 4; ++j) {
            const float bj = Mb[(kt << 6) + j * 16 + lo];
#pragma unroll
            for (int r = 0; r < 4; ++r) {
                const float s = sf[j][r] * 0.125f + bj;
                p[j][r] = s;
                tmax[r] = fmaxf(tmax[r], s);
            }
        }
#pragma unroll
        for (int r = 0; r < 4; ++r) {
            float t = tmax[r];
            t = fmaxf(t, __shfl_xor(t, 1));
            t = fmaxf(t, __shfl_xor(t, 2));
            t = fmaxf(t, __shfl_xor(t, 4));
            t = fmaxf(t, __shfl_xor(t, 8));
            const float mn = fmaxf(mr[r], t);
            corr[r] = __expf(mr[r] - mn);
            mr[r] = mn;
            tsum[r] = 0.f;
        }
#pragma unroll
        for (int j = 0; j < 4; ++j)
#pragma unroll
            for (int r = 0; r < 4; ++r) {
                p[j][r] = __expf(p[j][r] - mr[r]);
                tsum[r] += p[j][r];
            }
#pragma unroll
        for (int r = 0; r < 4; ++r) {
            float t = tsum[r];
            t += __shfl_xor(t, 1);
            t += __shfl_xor(t, 2);
            t += __shfl_xor(t, 4);
            t += __shfl_xor(t, 8);
            lr[r] = lr[r] * corr[r] + t;
        }
#pragma unroll
        for (int n = 0; n < 4; ++n)
#pragma unroll
            for (int r = 0; r < 4; ++r) accO[n][r] *= corr[r];

        // ---- P -> bf16 via wave-private LDS round-trip ----
        u16* Pw = Ps + (w << 10);
#pragma unroll
        for (int j = 0; j < 4; ++j)
#pragma unroll
            for (int r = 0; r < 4; ++r) {
                const int q = hi * 4 + r;
                const int key = j * 16 + lo;
                const int spz = (q & 7) ^ ((q >> 3) << 1);
                Pw[q * 64 + (key ^ (spz << 3))] = f2bf(p[j][r]);
            }
        const int spq = (lo & 7) ^ ((lo >> 3) << 1);
        const bf16x8 pa0 = *(const bf16x8*)&Pw[lo * 64 + ((hi * 8) ^ (spq << 3))];
        const bf16x8 pa1 = *(const bf16x8*)&Pw[lo * 64 + ((hi * 8 + 32) ^ (spq << 3))];

        // ---- PV ----
#pragma unroll
        for (int n = 0; n < 4; ++n) {
            const int d = n * 16 + lo;
            const int svz = (d & 7) ^ ((d >> 3) & 7);
            const bf16x8 v0f = *(const bf16x8*)&Vt[d * 64 + ((hi * 8) ^ (svz << 3))];
            const bf16x8 v1f = *(const bf16x8*)&Vt[d * 64 + ((hi * 8 + 32) ^ (svz << 3))];
            accO[n] = __builtin_amdgcn_mfma_f32_16x16x32_bf16(pa0, v0f, accO[n], 0, 0, 0);
            accO[n] = __builtin_amdgcn_mfma_f32_16x16x32_bf16(pa1, v1f, accO[n], 0, 0, 0);
        }
        __syncthreads();   // all waves done with Ks/Vt before restage
    }

#pragma unroll
    for (int n = 0; n < 4; ++n)
#pragma unroll
        for (int r = 0; r < 4; ++r) {
            const int q = hi * 4 + r;
            O[((size_t)(b * kS + q0 + w * 16 + q)) * kD + h * 64 + n * 16 + lo] =
                f2bf(accO[n][r] / lr[r]);
        }
}

// ---------------------------------------------------------------------------
// out = LayerNorm(a + r); dual-writes f32 (+ optional bf16)
// ---------------------------------------------------------------------------
__device__ __forceinline__ float block_sum(float v, float* red)
{
#pragma unroll
    for (int off = 32; off; off >>= 1) v += __shfl_xor(v, off);
    __syncthreads();
    if ((threadIdx.x & 63) == 0) red[threadIdx.x >> 6] = v;
    __syncthreads();
    return red[0] + red[1] + red[2] + red[3];
}

__global__ __launch_bounds__(256) void add_ln(
    const float* __restrict__ a, const float* __restrict__ r,
    const float* __restrict__ g, const float* __restrict__ bt,
    float* __restrict__ out, u16* __restrict__ outb)
{
    __shared__ float red[4];
    const size_t row = blockIdx.x;
    const int tid = threadIdx.x;
    float v[3];
    float s = 0.f;
#pragma unroll
    for (int j = 0; j < 3; ++j) {
        const int d = tid + (j << 8);
        v[j] = a[row * kD + d] + r[row * kD + d];
        s += v[j];
    }
    s = block_sum(s, red);
    const float mu = s * (1.f / 768.f);
    float vs = 0.f;
#pragma unroll
    for (int j = 0; j < 3; ++j) { const float t = v[j] - mu; vs = fmaf(t, t, vs); }
    vs = block_sum(vs, red);
    const float rstd = rsqrtf(vs * (1.f / 768.f) + 1e-5f);
#pragma unroll
    for (int j = 0; j < 3; ++j) {
        const int d = tid + (j << 8);
        const float o = (v[j] - mu) * rstd * g[d] + bt[d];
        out[row * kD + d] = o;
        if (outb) outb[row * kD + d] = f2bf(o);
    }
}

__global__ __launch_bounds__(256) void mean_s(
    const float* __restrict__ x, float* __restrict__ out)
{
    const int d = blockIdx.x * 256 + threadIdx.x;
    const int b = blockIdx.y;
    float s = 0.f;
    for (int t = 0; t < kS; ++t) s += x[((size_t)b * kS + t) * kD + d];
    out[b * kD + d] = s * (1.f / 2048.f);
}

// ---------------------------------------------------------------------------
// FALLBACK (round-1 f32 path) — used only if ws_size is too small
// ---------------------------------------------------------------------------
__global__ __launch_bounds__(256) void gemm_f32(
    const float* __restrict__ A, const float* __restrict__ W,
    const float* __restrict__ bias, float* __restrict__ C,
    int M, int N, int K, int relu)
{
    __shared__ float As[16][68];
    __shared__ float Bs[16][68];
    const int tid = threadIdx.x;
    const int row0 = blockIdx.x << 6;
    const int col0 = blockIdx.y << 6;
    const int tx = tid & 15, ty = tid >> 4;
    const int ar = tid >> 2;
    const int ak = (tid & 3) << 2;
    const int bk = tid >> 4;
    const int bc = (tid & 15) << 2;
    float acc[4][4] = {};
    const float* Ap = A + (size_t)(row0 + ar) * K + ak;
    const float* Wp = W + (size_t)bk * N + col0 + bc;
    for (int k0 = 0; k0 < K; k0 += 16) {
        const float4 a4 = *(const float4*)(Ap + k0);
        const float4 b4 = *(const float4*)(Wp + (size_t)k0 * N);
        __syncthreads();
        As[ak + 0][ar] = a4.x; As[ak + 1][ar] = a4.y;
        As[ak + 2][ar] = a4.z; As[ak + 3][ar] = a4.w;
        *(float4*)&Bs[bk][bc] = b4;
        __syncthreads();
#pragma unroll
        for (int kk = 0; kk < 16; ++kk) {
            const float4 av = *(const float4*)&As[kk][ty << 2];
            const float4 bv = *(const float4*)&Bs[kk][tx << 2];
            const float aa[4] = {av.x, av.y, av.z, av.w};
            const float bb[4] = {bv.x, bv.y, bv.z, bv.w};
#pragma unroll
            for (int i = 0; i < 4; ++i)
#pragma unroll
                for (int j = 0; j < 4; ++j)
                    acc[i][j] = fmaf(aa[i], bb[j], acc[i][j]);
        }
    }
#pragma unroll
    for (int i = 0; i < 4; ++i) {
        const int row = row0 + (ty << 2) + i;
#pragma unroll
        for (int j = 0; j < 4; ++j) {
            const int col = col0 + (tx << 2) + j;
            float v = acc[i][j] + bias[col];
            if (relu) v = fmaxf(v, 0.f);
            C[(size_t)row * N + col] = v;
        }
    }
}

__global__ __launch_bounds__(256) void attn_fused(
    const float* __restrict__ Q, const float* __restrict__ Km,
    const float* __restrict__ Vm, const int* __restrict__ ids,
    float* __restrict__ O)
{
    __shared__ float Ksf[64 * 64];
    __shared__ float Vtf[64 * 64];
    __shared__ float Qs[16][64];
    __shared__ float Psf[4][4][64];
    const int tid = threadIdx.x;
    const int w = tid >> 6;
    const int lane = tid & 63;
    const int h = blockIdx.y, b = blockIdx.z;
    const int qrow0 = blockIdx.x << 4;
    {
        const int r = tid >> 4;
        const int c4 = tid & 15;
        const float4 q4 = *(const float4*)(
            Q + ((size_t)(b * kS + qrow0 + r)) * kD + h * 64 + (c4 << 2));
        Qs[r][(c4 << 2) + 0] = q4.x * 0.125f;
        Qs[r][(c4 << 2) + 1] = q4.y * 0.125f;
        Qs[r][(c4 << 2) + 2] = q4.z * 0.125f;
        Qs[r][(c4 << 2) + 3] = q4.w * 0.125f;
    }
    float m[4], lsum[4], o[4];
#pragma unroll
    for (int r = 0; r < 4; ++r) { m[r] = -3.0e38f; lsum[r] = 0.f; o[r] = 0.f; }
    for (int kt = 0; kt < kS / 64; ++kt) {
        __syncthreads();
#pragma unroll
        for (int i = 0; i < 4; ++i) {
            const int lin = tid + (i << 8);
            const int row = lin >> 4;
            const int s4 = lin & 15;
            const size_t gro = ((size_t)(b * kS + (kt << 6) + row)) * kD + h * 64 + (s4 << 2);
            const float4 k4 = *(const float4*)(Km + gro);
            ((float4*)Ksf)[(row << 4) + (s4 ^ (row & 7))] = k4;
            const float4 v4 = *(const float4*)(Vm + gro);
            const int ksl = row >> 2, ke = row & 3;
            const int d0 = s4 << 2;
            Vtf[(d0 + 0) * 64 + ((ksl ^ ((d0 + 0) & 7)) << 2) + ke] = v4.x;
            Vtf[(d0 + 1) * 64 + ((ksl ^ ((d0 + 1) & 7)) << 2) + ke] = v4.y;
            Vtf[(d0 + 2) * 64 + ((ksl ^ ((d0 + 2) & 7)) << 2) + ke] = v4.z;
            Vtf[(d0 + 3) * 64 + ((ksl ^ ((d0 + 3) & 7)) << 2) + ke] = v4.w;
        }
        __syncthreads();
        const bool masked = (ids[(size_t)b * kS + (kt << 6) + lane] == 1);
        float scr[4] = {0.f, 0.f, 0.f, 0.f};
#pragma unroll
        for (int i16 = 0; i16 < 16; ++i16) {
            const float4 kv = ((const float4*)Ksf)[(lane << 4) + (i16 ^ (lane & 7))];
#pragma unroll
            for (int r = 0; r < 4; ++r) {
                const float4 qv = *(const float4*)&Qs[(w << 2) + r][i16 << 2];
                scr[r] = fmaf(kv.x, qv.x, fmaf(kv.y, qv.y,
                          fmaf(kv.z, qv.z, fmaf(kv.w, qv.w, scr[r]))));
            }
        }
#pragma unroll
        for (int r = 0; r < 4; ++r) {
            float sm = masked ? -3.0e38f : scr[r];
#pragma unroll
            for (int off = 32; off; off >>= 1) sm = fmaxf(sm, __shfl_xor(sm, off));
            const float mn = fmaxf(m[r], sm);
            const float cr = __expf(m[r] - mn);
            const float pv = masked ? 0.f : __expf(scr[r] - mn);
            float ps = pv;
#pragma unroll
            for (int off = 32; off; off >>= 1) ps += __shfl_xor(ps, off);
            lsum[r] = lsum[r] * cr + ps;
            o[r] *= cr;
            m[r] = mn;
            Psf[w][r][lane] = pv;
        }
#pragma unroll
        for (int i16 = 0; i16 < 16; ++i16) {
            const float4 vv = ((const float4*)Vtf)[(lane << 4) + (i16 ^ (lane & 7))];
#pragma unroll
            for (int r = 0; r < 4; ++r) {
                const float4 pv = *(const float4*)&Psf[w][r][i16 << 2];
                o[r] = fmaf(pv.x, vv.x, fmaf(pv.y, vv.y,
                        fmaf(pv.z, vv.z, fmaf(pv.w, vv.w, o[r]))));
            }
        }
    }
#pragma unroll
    for (int r = 0; r < 4; ++r)
        O[((size_t)(b * kS + qrow0 + (w << 2) + r)) * kD + h * 64 + lane] =
            o[r] / lsum[r];
}

// ---------------------------------------------------------------------------
// Host orchestration
// ---------------------------------------------------------------------------
extern "C" void kernel_launch(void* const* d_in, const int* in_sizes, int n_in,
                              void* d_out, int out_size, void* d_ws, size_t ws_size,
                              hipStream_t stream)
{
    const int*   ids   = (const int*)  d_in[0];
    const float* emb   = (const float*)d_in[1];
    const float* Wq    = (const float*)d_in[2];
    const float* bq    = (const float*)d_in[3];
    const float* Wk    = (const float*)d_in[4];
    const float* bk    = (const float*)d_in[5];
    const float* Wv    = (const float*)d_in[6];
    const float* bv    = (const float*)d_in[7];
    const float* Wo    = (const float*)d_in[8];
    const float* bo    = (const float*)d_in[9];
    const float* W1    = (const float*)d_in[10];
    const float* b1    = (const float*)d_in[11];
    const float* W2    = (const float*)d_in[12];
    const float* b2    = (const float*)d_in[13];
    const float* gamma = (const float*)d_in[14];
    const float* beta  = (const float*)d_in[15];
    float* out = (float*)d_out;

    const size_t BUFE = (size_t)kB * kS * kD;            // 6,291,456
    const size_t WDD  = (size_t)kD * kD;                 // 589,824
    const size_t WDF  = (size_t)kD * kF;                 // 2,359,296
    const int NTOK = kB * kS;                            // 8192

    const size_t FAST_NEED = 3 * BUFE * 4 + 4 * BUFE * 2 +
                             (4 * WDD + 2 * WDF) * 2 + (size_t)NTOK * 4;

    if (ws_size >= FAST_NEED) {
        // -------- fast bf16 MFMA path --------
        float* xb  = (float*)d_ws;
        float* x1  = xb + BUFE;
        float* ob  = x1 + BUFE;
        u16*   abf = (u16*)(ob + BUFE);
        u16*   qbf = abf + BUFE;
        u16*   kbf = qbf + BUFE;
        u16*   vbf = kbf + BUFE;
        u16*   wqt = vbf + BUFE;
        u16*   wkt = wqt + WDD;
        u16*   wvt = wkt + WDD;
        u16*   wot = wvt + WDD;
        u16*   w1t = wot + WDD;
        u16*   w2t = w1t + WDF;
        float* mbf = (float*)(w2t + WDF);
        u16*   hbf = kbf;                                // hidden chunk (spans kbf+vbf)

        embed_pe<<<NTOK, 256, 0, stream>>>(ids, emb, xb, abf);
        mk_mask<<<NTOK / 256, 256, 0, stream>>>(ids, mbf);

        for (int l = 0; l < kL; ++l) {
            const size_t oDD = (size_t)l * WDD;
            const size_t oDF = (size_t)l * WDF;
            const float* bql = bq + (size_t)l * kD;
            const float* bkl = bk + (size_t)l * kD;
            const float* bvl = bv + (size_t)l * kD;
            const float* bol = bo + (size_t)l * kD;
            const float* b1l = b1 + (size_t)l * kF;
            const float* b2l = b2 + (size_t)l * kD;
            const float* gl  = gamma + (size_t)l * kD;
            const float* btl = beta  + (size_t)l * kD;

            cvt_wT<<<dim3(12, 12), 256, 0, stream>>>(Wq + oDD, wqt, kD, kD);
            cvt_wT<<<dim3(12, 12), 256, 0, stream>>>(Wk + oDD, wkt, kD, kD);
            cvt_wT<<<dim3(12, 12), 256, 0, stream>>>(Wv + oDD, wvt, kD, kD);
            cvt_wT<<<dim3(12, 12), 256, 0, stream>>>(Wo + oDD, wot, kD, kD);
            cvt_wT<<<dim3(12, 48), 256, 0, stream>>>(W1 + oDF, w1t, kD, kF);
            cvt_wT<<<dim3(48, 12), 256, 0, stream>>>(W2 + oDF, w2t, kF, kD);

            gemm_bf16<<<dim3(64, 6), 256, 0, stream>>>(abf, wqt, bql, qbf,
                NTOK, kD, kD, 1);
            gemm_bf16<<<dim3(64, 6), 256, 0, stream>>>(abf, wkt, bkl, kbf,
                NTOK, kD, kD, 1);
            gemm_bf16<<<dim3(64, 6), 256, 0, stream>>>(abf, wvt, bvl, vbf,
                NTOK, kD, kD, 1);

            attn_mfma<<<dim3(kS / 64, kH, kB), 256, 0, stream>>>(
                qbf, kbf, vbf, mbf, abf);                // attn out -> abf

            gemm_bf16<<<dim3(64, 6), 256, 0, stream>>>(abf, wot, bol, ob,
                NTOK, kD, kD, 0);

            add_ln<<<NTOK, 256, 0, stream>>>(xb, ob, gl, btl, x1, qbf);

            for (int c = 0; c < 2; ++c) {
                const size_t ro = (size_t)c * 4096;
                gemm_bf16<<<dim3(32, 24), 256, 0, stream>>>(
                    qbf + ro * kD, w1t, b1l, hbf, 4096, kF, kD, 2);
                gemm_bf16<<<dim3(32, 6), 256, 0, stream>>>(
                    hbf, w2t, b2l, ob + ro * kD, 4096, kD, kF, 0);
            }

            add_ln<<<NTOK, 256, 0, stream>>>(x1, ob, gl, btl, xb, abf);
        }

        mean_s<<<dim3(kD / 256, kB), 256, 0, stream>>>(xb, out);
        return;
    }

    // -------- fallback f32 path (round-1) --------
    if (ws_size < 5 * BUFE * sizeof(float)) return;
    float* xb = (float*)d_ws;
    float* kb = xb + BUFE;
    float* qb = kb + BUFE;
    float* vb = qb + BUFE;
    float* obf = vb + BUFE;
    float* hb = qb;

    embed_pe<<<NTOK, 256, 0, stream>>>(ids, emb, xb, nullptr);
    for (int l = 0; l < kL; ++l) {
        const size_t oDD = (size_t)l * WDD;
        const size_t oDF = (size_t)l * WDF;
        gemm_f32<<<dim3(NTOK / 64, kD / 64), 256, 0, stream>>>(
            xb, Wq + oDD, bq + (size_t)l * kD, qb, NTOK, kD, kD, 0);
        gemm_f32<<<dim3(NTOK / 64, kD / 64), 256, 0, stream>>>(
            xb, Wk + oDD, bk + (size_t)l * kD, kb, NTOK, kD, kD, 0);
        gemm_f32<<<dim3(NTOK / 64, kD / 64), 256, 0, stream>>>(
            xb, Wv + oDD, bv + (size_t)l * kD, vb, NTOK, kD, kD, 0);
        attn_fused<<<dim3(kS / 16, kH, kB), 256, 0, stream>>>(qb, kb, vb, ids, obf);
        gemm_f32<<<dim3(NTOK / 64, kD / 64), 256, 0, stream>>>(
            obf, Wo + oDD, bo + (size_t)l * kD, qb, NTOK, kD, kD, 0);
        add_ln<<<NTOK, 256, 0, stream>>>(xb, qb,
            gamma + (size_t)l * kD, beta + (size_t)l * kD, kb, nullptr);
        for (int c = 0; c < 2; ++c) {
            const size_t ro = (size_t)c * 4096;
            gemm_f32<<<dim3(4096 / 64, kF / 64), 256, 0, stream>>>(
                kb + ro * kD, W1 + oDF, b1 + (size_t)l * kF, hb, 4096, kF, kD, 1);
            gemm_f32<<<dim3(4096 / 64, kD / 64), 256, 0, stream>>>(
                hb, W2 + oDF, b2 + (size_t)l * kD, obf + ro * kD, 4096, kD, kF, 0);
        }
        add_ln<<<NTOK, 256, 0, stream>>>(kb, obf,
            gamma + (size_t)l * kD, beta + (size_t)l * kD, xb, nullptr);
    }
    mean_s<<<dim3(kD / 256, kB), 256, 0, stream>>>(xb, out);
}

// Round 4
// 2302.148 us; speedup vs baseline: 1.4545x; 1.4545x over previous
//
#include <hip/hip_runtime.h>
#include <hip/hip_bf16.h>
#include <math.h>

typedef unsigned short u16;
typedef unsigned long long u64;
using bf16x8 = __attribute__((ext_vector_type(8))) short;
using f32x4  = __attribute__((ext_vector_type(4))) float;

static constexpr int kD = 768;
static constexpr int kH = 12;
static constexpr int kL = 6;
static constexpr int kF = 3072;
static constexpr int kS = 2048;
static constexpr int kB = 4;
static constexpr int kQW = 2304;          // fused QKV width

__device__ __forceinline__ u16 f2bf(float f) {
    return __bfloat16_as_ushort(__float2bfloat16(f));
}

__device__ __forceinline__ unsigned cvtpk(float a, float b) {
    unsigned d;
    asm volatile("v_cvt_pk_bf16_f32 %0, %1, %2" : "=v"(d) : "v"(a), "v"(b));
    return d;
}

__device__ __forceinline__ void gload16(const void* g, void* l) {
    auto gp = reinterpret_cast<const __attribute__((address_space(1))) unsigned int*>(
        reinterpret_cast<uintptr_t>(g));
    auto lp = reinterpret_cast<__attribute__((address_space(3))) unsigned int*>(
        reinterpret_cast<uintptr_t>(l));
    __builtin_amdgcn_global_load_lds(gp, lp, 16, 0, 0);
}

// ---------------------------------------------------------------------------
// Embedding + sinusoidal PE; dual-writes f32 residual + bf16 copy
// ---------------------------------------------------------------------------
__global__ __launch_bounds__(256) void embed_pe(
    const int* __restrict__ ids, const float* __restrict__ emb,
    float* __restrict__ x, u16* __restrict__ xbf)
{
    const int t = blockIdx.x;
    const int s = t & (kS - 1);
    const int id = ids[t];
#pragma unroll
    for (int j = 0; j < 3; ++j) {
        const int d = threadIdx.x + (j << 8);
        const float i2 = (float)((d >> 1) << 1);
        const float dv = __expf(i2 * (-9.210340371976184f / 768.f));
        const float ang = (float)s * dv;
        const float pe = (d & 1) ? cosf(ang) : sinf(ang);
        const float v = emb[(size_t)id * kD + d] + pe;
        x[(size_t)t * kD + d] = v;
        if (xbf) xbf[(size_t)t * kD + d] = f2bf(v);
    }
}

// mask bitmask: bit k of word (b*32+kt) = (ids[b*2048+kt*64+k] != 1)
__global__ __launch_bounds__(64) void mk_maskbits(const int* __restrict__ ids,
                                                  u64* __restrict__ mbits)
{
    const int w = blockIdx.x;
    const int lane = threadIdx.x;
    const u64 m = __ballot(ids[(size_t)w * 64 + lane] != 1);
    if (lane == 0) mbits[w] = m;
}

// bias arena: per layer 6912 floats: [qkv(bq*0.125|bk|bv) | bo | b1 | b2]
__global__ __launch_bounds__(256) void bias_build(
    const float* __restrict__ bq, const float* __restrict__ bk,
    const float* __restrict__ bv, const float* __restrict__ bo,
    const float* __restrict__ b1, const float* __restrict__ b2,
    float* __restrict__ ba)
{
    const int i = blockIdx.x * 256 + threadIdx.x;
    if (i >= 6 * 6912) return;
    const int l = i / 6912, p = i % 6912;
    float v;
    if      (p < 768)  v = bq[l * 768 + p] * 0.125f;
    else if (p < 1536) v = bk[l * 768 + p - 768];
    else if (p < 2304) v = bv[l * 768 + p - 1536];
    else if (p < 3072) v = bo[l * 768 + p - 2304];
    else if (p < 6144) v = b1[(size_t)l * 3072 + p - 3072];
    else               v = b2[l * 768 + p - 6144];
    ba[i] = v;
}

// ---------------------------------------------------------------------------
// Per-layer weight converter: all 6 matrices -> transposed bf16 arena.
// arena: [0) wqkvT[2304][768] | OFF_WO) woT[768][768] | OFF_W1) w1T[3072][768]
//        | OFF_W2) w2T[768][3072]
// grid 1728 tiles of 64x64.
// ---------------------------------------------------------------------------
static constexpr size_t OFF_WO = (size_t)2304 * 768;
static constexpr size_t OFF_W1 = OFF_WO + (size_t)768 * 768;
static constexpr size_t OFF_W2 = OFF_W1 + (size_t)3072 * 768;
static constexpr size_t WARENA_E = OFF_W2 + (size_t)768 * 3072;

__global__ __launch_bounds__(256) void cvt_all(
    const float* __restrict__ Wq, const float* __restrict__ Wk,
    const float* __restrict__ Wv, const float* __restrict__ Wo,
    const float* __restrict__ W1, const float* __restrict__ W2,
    u16* __restrict__ wa)
{
    __shared__ float T[64][68];
    const int t = blockIdx.x;
    const float* S; u16* Dp; int Nsrc, Kdst, srow0, scol0; float sc = 1.f;
    if (t < 432) {                         // wqkv: dst rows 2304, cols 768
        const int ni = t % 36, ki = t / 36;
        const int ng = ni * 64;
        const int sel = ng / 768;
        scol0 = ng % 768; srow0 = ki * 64;
        S = (sel == 0) ? Wq : (sel == 1) ? Wk : Wv;
        if (sel == 0) sc = 0.125f;
        Nsrc = 768; Kdst = 768;
        Dp = wa + (size_t)ng * 768 + srow0;
    } else if (t < 576) {                  // wo
        const int tt = t - 432; const int ni = tt % 12, ki = tt / 12;
        scol0 = ni * 64; srow0 = ki * 64;
        S = Wo; Nsrc = 768; Kdst = 768;
        Dp = wa + OFF_WO + (size_t)(ni * 64) * 768 + srow0;
    } else if (t < 1152) {                 // w1: dst [3072][768], src [768][3072]
        const int tt = t - 576; const int ni = tt % 48, ki = tt / 48;
        scol0 = ni * 64; srow0 = ki * 64;
        S = W1; Nsrc = 3072; Kdst = 768;
        Dp = wa + OFF_W1 + (size_t)(ni * 64) * 768 + srow0;
    } else {                               // w2: dst [768][3072], src [3072][768]
        const int tt = t - 1152; const int ni = tt % 12, ki = tt / 12;
        scol0 = ni * 64; srow0 = ki * 64;
        S = W2; Nsrc = 768; Kdst = 3072;
        Dp = wa + OFF_W2 + (size_t)(ni * 64) * 3072 + srow0;
    }
    const int tid = threadIdx.x;
#pragma unroll
    for (int i = 0; i < 4; ++i) {
        const int idx = tid + (i << 8);
        const int kr = idx >> 4;
        const int nc = (idx & 15) << 2;
        const float4 v = *(const float4*)(S + (size_t)(srow0 + kr) * Nsrc + scol0 + nc);
        T[kr][nc] = v.x; T[kr][nc + 1] = v.y; T[kr][nc + 2] = v.z; T[kr][nc + 3] = v.w;
    }
    __syncthreads();
#pragma unroll
    for (int i = 0; i < 4; ++i) {
        const int idx = tid + (i << 8);
        const int nr = idx >> 4;
        const int kc = (idx & 15) << 2;
        ushort4 o;
        o.x = f2bf(T[kc][nr] * sc);     o.y = f2bf(T[kc + 1][nr] * sc);
        o.z = f2bf(T[kc + 2][nr] * sc); o.w = f2bf(T[kc + 3][nr] * sc);
        *(ushort4*)(Dp + (size_t)nr * Kdst + kc) = o;
    }
}

// ---------------------------------------------------------------------------
// bf16 MFMA GEMM, 128x128 tile, BK=32, 2-phase counted-vmcnt pipeline.
// C[M,N] = A[M,K] @ Bt[N,K]^T + bias. mode: 0=f32 out, 1=bf16, 2=bf16+ReLU
// ---------------------------------------------------------------------------
__global__ __launch_bounds__(256) void gemm_bf16(
    const u16* __restrict__ A, const u16* __restrict__ Bt,
    const float* __restrict__ bias, void* __restrict__ Cv,
    int M, int N, int K, int mode)
{
    __shared__ u16 As[2][4096];
    __shared__ u16 Bs[2][4096];
    const int tid = threadIdx.x;
    const int l = tid & 63;
    const int lo = l & 15, hi = l >> 4;
    const int w = tid >> 6, wr = w >> 1, wc = w & 1;
    const size_t row0 = (size_t)blockIdx.x * 128;
    const size_t col0 = (size_t)blockIdx.y * 128;

    const int c0 = tid, c1 = tid + 256;
    const int r0 = c0 >> 2, g0 = (c0 & 3) ^ ((r0 >> 1) & 3);
    const int r1 = c1 >> 2, g1 = (c1 & 3) ^ ((r1 >> 1) & 3);
    const u16* a0 = A  + (row0 + r0) * K + g0 * 8;
    const u16* a1 = A  + (row0 + r1) * K + g1 * 8;
    const u16* b0 = Bt + (col0 + r0) * K + g0 * 8;
    const u16* b1 = Bt + (col0 + r1) * K + g1 * 8;

    f32x4 acc[4][4];
#pragma unroll
    for (int i = 0; i < 4; ++i)
#pragma unroll
        for (int j = 0; j < 4; ++j)
#pragma unroll
            for (int r = 0; r < 4; ++r) acc[i][j][r] = 0.f;

    int aoff[4], boff[4];
#pragma unroll
    for (int i = 0; i < 4; ++i) {
        const int ra = wr * 64 + i * 16 + lo;
        aoff[i] = ra * 32 + ((hi ^ ((ra >> 1) & 3)) << 3);
        const int rb = wc * 64 + i * 16 + lo;
        boff[i] = rb * 32 + ((hi ^ ((rb >> 1) & 3)) << 3);
    }

    const int NT = K >> 5;
    // prologue: stage tile 0
    gload16(a0, As[0] + c0 * 8);
    gload16(a1, As[0] + c1 * 8);
    gload16(b0, Bs[0] + c0 * 8);
    gload16(b1, Bs[0] + c1 * 8);

    int cur = 0;
    for (int t = 0; t < NT; ++t) {
        if (t + 1 < NT) {
            const int k0 = (t + 1) << 5;
            const int nb = cur ^ 1;
            gload16(a0 + k0, As[nb] + c0 * 8);
            gload16(a1 + k0, As[nb] + c1 * 8);
            gload16(b0 + k0, Bs[nb] + c0 * 8);
            gload16(b1 + k0, Bs[nb] + c1 * 8);
            asm volatile("s_waitcnt vmcnt(4)" ::: "memory");
        } else {
            asm volatile("s_waitcnt vmcnt(0)" ::: "memory");
        }
        __builtin_amdgcn_s_barrier();
        bf16x8 af[4], bfr[4];
#pragma unroll
        for (int i = 0; i < 4; ++i) af[i]  = *(const bf16x8*)&As[cur][aoff[i]];
#pragma unroll
        for (int j = 0; j < 4; ++j) bfr[j] = *(const bf16x8*)&Bs[cur][boff[j]];
#pragma unroll
        for (int i = 0; i < 4; ++i)
#pragma unroll
            for (int j = 0; j < 4; ++j)
                acc[i][j] = __builtin_amdgcn_mfma_f32_16x16x32_bf16(
                    af[i], bfr[j], acc[i][j], 0, 0, 0);
        asm volatile("s_waitcnt lgkmcnt(0)" ::: "memory");
        __builtin_amdgcn_sched_barrier(0);
        __builtin_amdgcn_s_barrier();
        cur ^= 1;
    }

#pragma unroll
    for (int i = 0; i < 4; ++i) {
        const size_t rbase = row0 + wr * 64 + i * 16 + hi * 4;
#pragma unroll
        for (int j = 0; j < 4; ++j) {
            const size_t c = col0 + wc * 64 + j * 16 + lo;
            const float bs = bias[c];
#pragma unroll
            for (int r = 0; r < 4; ++r) {
                float v = acc[i][j][r] + bs;
                if (mode == 2) v = fmaxf(v, 0.f);
                const size_t off = (rbase + r) * (size_t)N + c;
                if (mode == 0) ((float*)Cv)[off] = v;
                else           ((u16*)Cv)[off]  = f2bf(v);
            }
        }
    }
}

// ---------------------------------------------------------------------------
// MFMA flash attention v2 — swapped QK^T, in-register softmax.
// QKV fused buffer [B*S][2304] (Q pre-scaled by 1/8). Block: 4 waves x 16 q.
// Per lane (lo,hi): P[q=lo][key=j*16+hi*4+r].  Grid (S/64, H, B).
// ---------------------------------------------------------------------------
__global__ __launch_bounds__(256) void attn_mfma(
    const u16* __restrict__ QKV, const u64* __restrict__ mbits,
    u16* __restrict__ O)
{
    __shared__ u16 Ks[4096];          // [key][64dk], slot-swizzled
    __shared__ u16 Vt[4096];          // [dk][64key], slot-swizzled
    __shared__ u16 PT[4][1024];       // per wave: [q=16][key=64], swizzled

    const int tid = threadIdx.x, l = tid & 63, w = tid >> 6;
    const int lo = l & 15, hi = l >> 4;
    const int h = blockIdx.y, b = blockIdx.z;
    const int q0 = blockIdx.x << 6;

    // Q B-frag (already scaled by 1/8): rows q0 + w*16 + lo
    bf16x8 qf0, qf1;
    {
        const u16* qp = QKV + ((size_t)(b * kS + q0 + w * 16 + lo)) * kQW
                            + h * 64 + hi * 8;
        qf0 = *(const bf16x8*)qp;
        qf1 = *(const bf16x8*)(qp + 32);
    }

    // staging geometry: granule g in [0,512): key=g>>3, slot x=g&7
    const int ga = tid, gb = tid + 256;
    const int keyA = ga >> 3, sxA = ga & 7, EA = sxA ^ (keyA & 7);
    const int keyB = gb >> 3, sxB = gb & 7, EB = sxB ^ (keyB & 7);
    const u16* Kbase = QKV + 768  + (size_t)(b * kS) * kQW + h * 64;
    const u16* Vbase = QKV + 1536 + (size_t)(b * kS) * kQW + h * 64;

    f32x4 accO[4];
#pragma unroll
    for (int n = 0; n < 4; ++n)
#pragma unroll
        for (int r = 0; r < 4; ++r) accO[n][r] = 0.f;
    float m = -3.0e38f, lsum = 0.f;

    const int ksw = (lo & 7) << 3;

    for (int kt = 0; kt < kS / 64; ++kt) {
        const size_t tb = (size_t)(kt << 6) * kQW;
        // K: direct global->LDS with pre-swizzled source granule
        gload16(Kbase + tb + (size_t)keyA * kQW + EA * 8, Ks + ga * 8);
        gload16(Kbase + tb + (size_t)keyB * kQW + EB * 8, Ks + gb * 8);
        // V: transpose-scatter
#pragma unroll
        for (int i = 0; i < 2; ++i) {
            const int key = i ? keyB : keyA;
            const int e0 = (i ? sxB : sxA) << 3;
            union { uint4 u; u16 s[8]; } vv;
            vv.u = *(const uint4*)(Vbase + tb + (size_t)key * kQW + e0);
#pragma unroll
            for (int e = 0; e < 8; ++e) {
                const int d = e0 + e;
                const int svz = (d & 7) ^ ((d >> 3) & 7);
                Vt[d * 64 + (key ^ (svz << 3))] = vv.s[e];
            }
        }
        __syncthreads();

        // ---- scores S^T: A=K rows, B=Q. Lane: q=lo, keys j*16+hi*4+r ----
        f32x4 st[4];
        __builtin_amdgcn_s_setprio(1);
#pragma unroll
        for (int j = 0; j < 4; ++j) {
#pragma unroll
            for (int r = 0; r < 4; ++r) st[j][r] = 0.f;
            const int kb = (j * 16 + lo) * 64;
            const bf16x8 k0 = *(const bf16x8*)&Ks[kb + ((hi * 8)      ^ ksw)];
            const bf16x8 k1 = *(const bf16x8*)&Ks[kb + ((hi * 8 + 32) ^ ksw)];
            st[j] = __builtin_amdgcn_mfma_f32_16x16x32_bf16(k0, qf0, st[j], 0, 0, 0);
            st[j] = __builtin_amdgcn_mfma_f32_16x16x32_bf16(k1, qf1, st[j], 0, 0, 0);
        }
        __builtin_amdgcn_s_setprio(0);

        // ---- online softmax, row = q = lo ----
        float rmax = st[0][0];
#pragma unroll
        for (int j = 0; j < 4; ++j)
#pragma unroll
            for (int r = 0; r < 4; ++r) rmax = fmaxf(rmax, st[j][r]);
        rmax = fmaxf(rmax, __shfl_xor(rmax, 16));
        rmax = fmaxf(rmax, __shfl_xor(rmax, 32));

        const bool skip = __all(rmax <= m + 8.0f);
        if (!skip) {
            const float mn = fmaxf(m, rmax);
            const float corr = __expf(m - mn);
            m = mn;
            lsum *= corr;
            float c2[4];
#pragma unroll
            for (int r = 0; r < 4; ++r) c2[r] = __shfl(corr, hi * 4 + r);
#pragma unroll
            for (int n = 0; n < 4; ++n)
#pragma unroll
                for (int r = 0; r < 4; ++r) accO[n][r] *= c2[r];
        }

#pragma unroll
        for (int j = 0; j < 4; ++j)
#pragma unroll
            for (int r = 0; r < 4; ++r) st[j][r] = __expf(st[j][r] - m);

        const u64 mb = mbits[b * 32 + kt];
        if (mb != ~0ull) {
#pragma unroll
            for (int j = 0; j < 4; ++j)
#pragma unroll
                for (int r = 0; r < 4; ++r)
                    if (!((mb >> (j * 16 + hi * 4 + r)) & 1)) st[j][r] = 0.f;
        }

        float ts = 0.f;
#pragma unroll
        for (int j = 0; j < 4; ++j)
#pragma unroll
            for (int r = 0; r < 4; ++r) ts += st[j][r];
        ts += __shfl_xor(ts, 16);
        ts += __shfl_xor(ts, 32);
        lsum += ts;

        // ---- pack P -> PT (wave-private, swizzled) ----
        u16* pw = PT[w];
#pragma unroll
        for (int j = 0; j < 4; ++j) {
            uint2 pk;
            pk.x = cvtpk(st[j][0], st[j][1]);
            pk.y = cvtpk(st[j][2], st[j][3]);
            *(uint2*)&pw[lo * 64 + (((j << 4) + (hi << 2)) ^ ksw)] = pk;
        }
        const bf16x8 pa0 = *(const bf16x8*)&pw[lo * 64 + ((hi * 8)      ^ ksw)];
        const bf16x8 pa1 = *(const bf16x8*)&pw[lo * 64 + ((hi * 8 + 32) ^ ksw)];

        // ---- PV: A=P, B=V^T ----
        __builtin_amdgcn_s_setprio(1);
#pragma unroll
        for (int n = 0; n < 4; ++n) {
            const int d = n * 16 + lo;
            const int svz = ((d & 7) ^ ((d >> 3) & 7)) << 3;
            const bf16x8 v0 = *(const bf16x8*)&Vt[d * 64 + ((hi * 8)      ^ svz)];
            const bf16x8 v1 = *(const bf16x8*)&Vt[d * 64 + ((hi * 8 + 32) ^ svz)];
            accO[n] = __builtin_amdgcn_mfma_f32_16x16x32_bf16(pa0, v0, accO[n], 0, 0, 0);
            accO[n] = __builtin_amdgcn_mfma_f32_16x16x32_bf16(pa1, v1, accO[n], 0, 0, 0);
        }
        __builtin_amdgcn_s_setprio(0);
        __syncthreads();
    }

    float linv[4];
#pragma unroll
    for (int r = 0; r < 4; ++r) linv[r] = 1.f / __shfl(lsum, hi * 4 + r);
#pragma unroll
    for (int n = 0; n < 4; ++n)
#pragma unroll
        for (int r = 0; r < 4; ++r)
            O[((size_t)(b * kS + q0 + w * 16 + hi * 4 + r)) * kD
              + h * 64 + n * 16 + lo] = f2bf(accO[n][r] * linv[r]);
}

// ---------------------------------------------------------------------------
// out = LayerNorm(a + r); wave-per-row, float4; dual f32 + optional bf16
// grid: B*S/4 blocks of 256
// ---------------------------------------------------------------------------
__global__ __launch_bounds__(256) void add_ln(
    const float* __restrict__ a, const float* __restrict__ r,
    const float* __restrict__ g, const float* __restrict__ bt,
    float* __restrict__ out, u16* __restrict__ outb)
{
    const int lane = threadIdx.x & 63;
    const size_t row = (size_t)blockIdx.x * 4 + (threadIdx.x >> 6);
    const float4* a4 = (const float4*)(a + row * kD);
    const float4* r4 = (const float4*)(r + row * kD);
    float4 v[3];
    float s = 0.f;
#pragma unroll
    for (int j = 0; j < 3; ++j) {
        const float4 av = a4[j * 64 + lane];
        const float4 rv = r4[j * 64 + lane];
        v[j].x = av.x + rv.x; v[j].y = av.y + rv.y;
        v[j].z = av.z + rv.z; v[j].w = av.w + rv.w;
        s += v[j].x + v[j].y + v[j].z + v[j].w;
    }
#pragma unroll
    for (int off = 32; off; off >>= 1) s += __shfl_xor(s, off);
    const float mu = s * (1.f / 768.f);
    float vs = 0.f;
#pragma unroll
    for (int j = 0; j < 3; ++j) {
        float t0 = v[j].x - mu, t1 = v[j].y - mu, t2 = v[j].z - mu, t3 = v[j].w - mu;
        vs = fmaf(t0, t0, fmaf(t1, t1, fmaf(t2, t2, fmaf(t3, t3, vs))));
    }
#pragma unroll
    for (int off = 32; off; off >>= 1) vs += __shfl_xor(vs, off);
    const float rstd = rsqrtf(vs * (1.f / 768.f) + 1e-5f);
    const float4* g4 = (const float4*)g;
    const float4* b4 = (const float4*)bt;
#pragma unroll
    for (int j = 0; j < 3; ++j) {
        const float4 gv = g4[j * 64 + lane];
        const float4 bv = b4[j * 64 + lane];
        float4 o;
        o.x = (v[j].x - mu) * rstd * gv.x + bv.x;
        o.y = (v[j].y - mu) * rstd * gv.y + bv.y;
        o.z = (v[j].z - mu) * rstd * gv.z + bv.z;
        o.w = (v[j].w - mu) * rstd * gv.w + bv.w;
        ((float4*)(out + row * kD))[j * 64 + lane] = o;
        if (outb) {
            ushort4 ob4;
            ob4.x = f2bf(o.x); ob4.y = f2bf(o.y);
            ob4.z = f2bf(o.z); ob4.w = f2bf(o.w);
            ((ushort4*)(outb + row * kD))[j * 64 + lane] = ob4;
        }
    }
}

__global__ __launch_bounds__(256) void mean_s(
    const float* __restrict__ x, float* __restrict__ out)
{
    const int d = blockIdx.x * 256 + threadIdx.x;
    const int b = blockIdx.y;
    float s = 0.f;
    for (int t = 0; t < kS; ++t) s += x[((size_t)b * kS + t) * kD + d];
    out[b * kD + d] = s * (1.f / 2048.f);
}

// ---------------------------------------------------------------------------
// FALLBACK f32 kernels (used only if ws too small)
// ---------------------------------------------------------------------------
__global__ __launch_bounds__(256) void gemm_f32(
    const float* __restrict__ A, const float* __restrict__ W,
    const float* __restrict__ bias, float* __restrict__ C,
    int M, int N, int K, int relu)
{
    __shared__ float As[16][68];
    __shared__ float Bs[16][68];
    const int tid = threadIdx.x;
    const int row0 = blockIdx.x << 6;
    const int col0 = blockIdx.y << 6;
    const int tx = tid & 15, ty = tid >> 4;
    const int ar = tid >> 2;
    const int ak = (tid & 3) << 2;
    const int bk = tid >> 4;
    const int bc = (tid & 15) << 2;
    float acc[4][4] = {};
    const float* Ap = A + (size_t)(row0 + ar) * K + ak;
    const float* Wp = W + (size_t)bk * N + col0 + bc;
    for (int k0 = 0; k0 < K; k0 += 16) {
        const float4 a4 = *(const float4*)(Ap + k0);
        const float4 b4 = *(const float4*)(Wp + (size_t)k0 * N);
        __syncthreads();
        As[ak + 0][ar] = a4.x; As[ak + 1][ar] = a4.y;
        As[ak + 2][ar] = a4.z; As[ak + 3][ar] = a4.w;
        *(float4*)&Bs[bk][bc] = b4;
        __syncthreads();
#pragma unroll
        for (int kk = 0; kk < 16; ++kk) {
            const float4 av = *(const float4*)&As[kk][ty << 2];
            const float4 bv = *(const float4*)&Bs[kk][tx << 2];
            const float aa[4] = {av.x, av.y, av.z, av.w};
            const float bb[4] = {bv.x, bv.y, bv.z, bv.w};
#pragma unroll
            for (int i = 0; i < 4; ++i)
#pragma unroll
                for (int j = 0; j < 4; ++j)
                    acc[i][j] = fmaf(aa[i], bb[j], acc[i][j]);
        }
    }
#pragma unroll
    for (int i = 0; i < 4; ++i) {
        const int row = row0 + (ty << 2) + i;
#pragma unroll
        for (int j = 0; j < 4; ++j) {
            const int col = col0 + (tx << 2) + j;
            float v = acc[i][j] + bias[col];
            if (relu) v = fmaxf(v, 0.f);
            C[(size_t)row * N + col] = v;
        }
    }
}

__global__ __launch_bounds__(256) void attn_fused(
    const float* __restrict__ Q, const float* __restrict__ Km,
    const float* __restrict__ Vm, const int* __restrict__ ids,
    float* __restrict__ O)
{
    __shared__ float Ksf[64 * 64];
    __shared__ float Vtf[64 * 64];
    __shared__ float Qs[16][64];
    __shared__ float Psf[4][4][64];
    const int tid = threadIdx.x;
    const int w = tid >> 6;
    const int lane = tid & 63;
    const int h = blockIdx.y, b = blockIdx.z;
    const int qrow0 = blockIdx.x << 4;
    {
        const int r = tid >> 4;
        const int c4 = tid & 15;
        const float4 q4 = *(const float4*)(
            Q + ((size_t)(b * kS + qrow0 + r)) * kD + h * 64 + (c4 << 2));
        Qs[r][(c4 << 2) + 0] = q4.x * 0.125f;
        Qs[r][(c4 << 2) + 1] = q4.y * 0.125f;
        Qs[r][(c4 << 2) + 2] = q4.z * 0.125f;
        Qs[r][(c4 << 2) + 3] = q4.w * 0.125f;
    }
    float m[4], lsum[4], o[4];
#pragma unroll
    for (int r = 0; r < 4; ++r) { m[r] = -3.0e38f; lsum[r] = 0.f; o[r] = 0.f; }
    for (int kt = 0; kt < kS / 64; ++kt) {
        __syncthreads();
#pragma unroll
        for (int i = 0; i < 4; ++i) {
            const int lin = tid + (i << 8);
            const int row = lin >> 4;
            const int s4 = lin & 15;
            const size_t gro = ((size_t)(b * kS + (kt << 6) + row)) * kD + h * 64 + (s4 << 2);
            const float4 k4 = *(const float4*)(Km + gro);
            ((float4*)Ksf)[(row << 4) + (s4 ^ (row & 7))] = k4;
            const float4 v4 = *(const float4*)(Vm + gro);
            const int ksl = row >> 2, ke = row & 3;
            const int d0 = s4 << 2;
            Vtf[(d0 + 0) * 64 + ((ksl ^ ((d0 + 0) & 7)) << 2) + ke] = v4.x;
            Vtf[(d0 + 1) * 64 + ((ksl ^ ((d0 + 1) & 7)) << 2) + ke] = v4.y;
            Vtf[(d0 + 2) * 64 + ((ksl ^ ((d0 + 2) & 7)) << 2) + ke] = v4.z;
            Vtf[(d0 + 3) * 64 + ((ksl ^ ((d0 + 3) & 7)) << 2) + ke] = v4.w;
        }
        __syncthreads();
        const bool masked = (ids[(size_t)b * kS + (kt << 6) + lane] == 1);
        float scr[4] = {0.f, 0.f, 0.f, 0.f};
#pragma unroll
        for (int i16 = 0; i16 < 16; ++i16) {
            const float4 kv = ((const float4*)Ksf)[(lane << 4) + (i16 ^ (lane & 7))];
#pragma unroll
            for (int r = 0; r < 4; ++r) {
                const float4 qv = *(const float4*)&Qs[(w << 2) + r][i16 << 2];
                scr[r] = fmaf(kv.x, qv.x, fmaf(kv.y, qv.y,
                          fmaf(kv.z, qv.z, fmaf(kv.w, qv.w, scr[r]))));
            }
        }
#pragma unroll
        for (int r = 0; r < 4; ++r) {
            float sm = masked ? -3.0e38f : scr[r];
#pragma unroll
            for (int off = 32; off; off >>= 1) sm = fmaxf(sm, __shfl_xor(sm, off));
            const float mn = fmaxf(m[r], sm);
            const float cr = __expf(m[r] - mn);
            const float pv = masked ? 0.f : __expf(scr[r] - mn);
            float ps = pv;
#pragma unroll
            for (int off = 32; off; off >>= 1) ps += __shfl_xor(ps, off);
            lsum[r] = lsum[r] * cr + ps;
            o[r] *= cr;
            m[r] = mn;
            Psf[w][r][lane] = pv;
        }
#pragma unroll
        for (int i16 = 0; i16 < 16; ++i16) {
            const float4 vv = ((const float4*)Vtf)[(lane << 4) + (i16 ^ (lane & 7))];
#pragma unroll
            for (int r = 0; r < 4; ++r) {
                const float4 pv = *(const float4*)&Psf[w][r][i16 << 2];
                o[r] = fmaf(pv.x, vv.x, fmaf(pv.y, vv.y,
                        fmaf(pv.z, vv.z, fmaf(pv.w, vv.w, o[r]))));
            }
        }
    }
#pragma unroll
    for (int r = 0; r < 4; ++r)
        O[((size_t)(b * kS + qrow0 + (w << 2) + r)) * kD + h * 64 + lane] =
            o[r] / lsum[r];
}

// ---------------------------------------------------------------------------
// Host orchestration
// ---------------------------------------------------------------------------
extern "C" void kernel_launch(void* const* d_in, const int* in_sizes, int n_in,
                              void* d_out, int out_size, void* d_ws, size_t ws_size,
                              hipStream_t stream)
{
    const int*   ids   = (const int*)  d_in[0];
    const float* emb   = (const float*)d_in[1];
    const float* Wq    = (const float*)d_in[2];
    const float* bq    = (const float*)d_in[3];
    const float* Wk    = (const float*)d_in[4];
    const float* bk    = (const float*)d_in[5];
    const float* Wv    = (const float*)d_in[6];
    const float* bv    = (const float*)d_in[7];
    const float* Wo    = (const float*)d_in[8];
    const float* bo    = (const float*)d_in[9];
    const float* W1    = (const float*)d_in[10];
    const float* b1    = (const float*)d_in[11];
    const float* W2    = (const float*)d_in[12];
    const float* b2    = (const float*)d_in[13];
    const float* gamma = (const float*)d_in[14];
    const float* beta  = (const float*)d_in[15];
    float* out = (float*)d_out;

    const size_t BUFE = (size_t)kB * kS * kD;          // 6,291,456
    const size_t WDD  = (size_t)kD * kD;
    const size_t WDF  = (size_t)kD * kF;
    const int NTOK = kB * kS;                          // 8192

    // fast-path workspace plan
    const size_t NEED = BUFE * 4 * 2                   // xb, ob (f32)
                      + BUFE * 2                       // abf
                      + (size_t)NTOK * kQW * 2         // qkv
                      + WARENA_E * 2                   // weight arena
                      + (size_t)6 * 6912 * 4           // bias arena
                      + 128 * 8;                       // mask bits

    if (ws_size >= NEED) {
        float* xb  = (float*)d_ws;
        float* ob  = xb + BUFE;
        u16*   abf = (u16*)(ob + BUFE);
        u16*   qkv = abf + BUFE;
        u16*   wa  = qkv + (size_t)NTOK * kQW;
        float* ba  = (float*)(wa + WARENA_E);
        u64*   mbt = (u64*)(ba + 6 * 6912);

        embed_pe<<<NTOK, 256, 0, stream>>>(ids, emb, xb, abf);
        mk_maskbits<<<kB * kS / 64, 64, 0, stream>>>(ids, mbt);
        bias_build<<<(6 * 6912 + 255) / 256, 256, 0, stream>>>(
            bq, bk, bv, bo, b1, b2, ba);

        for (int l = 0; l < kL; ++l) {
            const size_t oDD = (size_t)l * WDD;
            const size_t oDF = (size_t)l * WDF;
            const float* bl = ba + (size_t)l * 6912;
            const float* gl  = gamma + (size_t)l * kD;
            const float* btl = beta  + (size_t)l * kD;

            cvt_all<<<1728, 256, 0, stream>>>(
                Wq + oDD, Wk + oDD, Wv + oDD, Wo + oDD, W1 + oDF, W2 + oDF, wa);

            // fused QKV projection (Q pre-scaled 1/8)
            gemm_bf16<<<dim3(64, 18), 256, 0, stream>>>(
                abf, wa, bl, qkv, NTOK, kQW, kD, 1);

            attn_mfma<<<dim3(kS / 64, kH, kB), 256, 0, stream>>>(
                qkv, mbt, abf);                        // attn out -> abf

            gemm_bf16<<<dim3(64, 6), 256, 0, stream>>>(
                abf, wa + OFF_WO, bl + 2304, ob, NTOK, kD, kD, 0);

            // x1 = LN(x + o): f32 -> ob (in place), bf16 -> abf
            add_ln<<<NTOK / 4, 256, 0, stream>>>(xb, ob, gl, btl, ob, abf);

            // FFN in two 4096-row chunks; hidden reuses qkv buffer
            for (int c = 0; c < 2; ++c) {
                const size_t ro = (size_t)c * 4096;
                gemm_bf16<<<dim3(32, 24), 256, 0, stream>>>(
                    abf + ro * kD, wa + OFF_W1, bl + 3072, qkv, 4096, kF, kD, 2);
                gemm_bf16<<<dim3(32, 6), 256, 0, stream>>>(
                    qkv, wa + OFF_W2, bl + 6144, xb + ro * kD, 4096, kD, kF, 0);
            }

            // x = LN(x1 + ffn): f32 -> xb, bf16 -> abf
            add_ln<<<NTOK / 4, 256, 0, stream>>>(ob, xb, gl, btl, xb, abf);
        }

        mean_s<<<dim3(kD / 256, kB), 256, 0, stream>>>(xb, out);
        return;
    }

    // -------- fallback f32 path --------
    if (ws_size < 5 * BUFE * sizeof(float)) return;
    float* xb = (float*)d_ws;
    float* kb = xb + BUFE;
    float* qb = kb + BUFE;
    float* vb = qb + BUFE;
    float* obf = vb + BUFE;
    float* hb = qb;

    embed_pe<<<NTOK, 256, 0, stream>>>(ids, emb, xb, nullptr);
    for (int l = 0; l < kL; ++l) {
        const size_t oDD = (size_t)l * WDD;
        const size_t oDF = (size_t)l * WDF;
        gemm_f32<<<dim3(NTOK / 64, kD / 64), 256, 0, stream>>>(
            xb, Wq + oDD, bq + (size_t)l * kD, qb, NTOK, kD, kD, 0);
        gemm_f32<<<dim3(NTOK / 64, kD / 64), 256, 0, stream>>>(
            xb, Wk + oDD, bk + (size_t)l * kD, kb, NTOK, kD, kD, 0);
        gemm_f32<<<dim3(NTOK / 64, kD / 64), 256, 0, stream>>>(
            xb, Wv + oDD, bv + (size_t)l * kD, vb, NTOK, kD, kD, 0);
        attn_fused<<<dim3(kS / 16, kH, kB), 256, 0, stream>>>(qb, kb, vb, ids, obf);
        gemm_f32<<<dim3(NTOK / 64, kD / 64), 256, 0, stream>>>(
            obf, Wo + oDD, bo + (size_t)l * kD, qb, NTOK, kD, kD, 0);
        add_ln<<<NTOK / 4, 256, 0, stream>>>(xb, qb,
            gamma + (size_t)l * kD, beta + (size_t)l * kD, kb, nullptr);
        for (int c = 0; c < 2; ++c) {
            const size_t ro = (size_t)c * 4096;
            gemm_f32<<<dim3(4096 / 64, kF / 64), 256, 0, stream>>>(
                kb + ro * kD, W1 + oDF, b1 + (size_t)l * kF, hb, 4096, kF, kD, 1);
            gemm_f32<<<dim3(4096 / 64, kD / 64), 256, 0, stream>>>(
                hb, W2 + oDF, b2 + (size_t)l * kD, obf + ro * kD, 4096, kD, kF, 0);
        }
        add_ln<<<NTOK / 4, 256, 0, stream>>>(kb, obf,
            gamma + (size_t)l * kD, beta + (size_t)l * kD, xb, nullptr);
    }
    mean_s<<<dim3(kD / 256, kB), 256, 0, stream>>>(xb, out);
}

// Round 5
// 1870.849 us; speedup vs baseline: 1.7898x; 1.2305x over previous
//
#include <hip/hip_runtime.h>
#include <hip/hip_bf16.h>
#include <math.h>

typedef unsigned short u16;
typedef unsigned long long u64;
using bf16x8 = __attribute__((ext_vector_type(8))) short;
using f32x4  = __attribute__((ext_vector_type(4))) float;

static constexpr int kD = 768;
static constexpr int kH = 12;
static constexpr int kL = 6;
static constexpr int kF = 3072;
static constexpr int kS = 2048;
static constexpr int kB = 4;
static constexpr int kQW = 2304;          // fused QKV width

__device__ __forceinline__ u16 f2bf(float f) {
    return __bfloat16_as_ushort(__float2bfloat16(f));
}

__device__ __forceinline__ unsigned cvtpk(float a, float b) {
    unsigned d;
    asm volatile("v_cvt_pk_bf16_f32 %0, %1, %2" : "=v"(d) : "v"(a), "v"(b));
    return d;
}

__device__ __forceinline__ void gload16(const void* g, void* l) {
    auto gp = reinterpret_cast<const __attribute__((address_space(1))) unsigned int*>(
        reinterpret_cast<uintptr_t>(g));
    auto lp = reinterpret_cast<__attribute__((address_space(3))) unsigned int*>(
        reinterpret_cast<uintptr_t>(l));
    __builtin_amdgcn_global_load_lds(gp, lp, 16, 0, 0);
}

// ---------------------------------------------------------------------------
// Embedding + sinusoidal PE; dual-writes f32 residual + bf16 copy
// ---------------------------------------------------------------------------
__global__ __launch_bounds__(256) void embed_pe(
    const int* __restrict__ ids, const float* __restrict__ emb,
    float* __restrict__ x, u16* __restrict__ xbf)
{
    const int t = blockIdx.x;
    const int s = t & (kS - 1);
    const int id = ids[t];
#pragma unroll
    for (int j = 0; j < 3; ++j) {
        const int d = threadIdx.x + (j << 8);
        const float i2 = (float)((d >> 1) << 1);
        const float dv = __expf(i2 * (-9.210340371976184f / 768.f));
        const float ang = (float)s * dv;
        const float pe = (d & 1) ? cosf(ang) : sinf(ang);
        const float v = emb[(size_t)id * kD + d] + pe;
        x[(size_t)t * kD + d] = v;
        if (xbf) xbf[(size_t)t * kD + d] = f2bf(v);
    }
}

// mask bitmask: bit k of word (b*32+kt) = (ids[b*2048+kt*64+k] != 1)
__global__ __launch_bounds__(64) void mk_maskbits(const int* __restrict__ ids,
                                                  u64* __restrict__ mbits)
{
    const int w = blockIdx.x;
    const int lane = threadIdx.x;
    const u64 m = __ballot(ids[(size_t)w * 64 + lane] != 1);
    if (lane == 0) mbits[w] = m;
}

// bias arena: per layer 6912 floats: [qkv(bq*0.125|bk|bv) | bo | b1 | b2]
__global__ __launch_bounds__(256) void bias_build(
    const float* __restrict__ bq, const float* __restrict__ bk,
    const float* __restrict__ bv, const float* __restrict__ bo,
    const float* __restrict__ b1, const float* __restrict__ b2,
    float* __restrict__ ba)
{
    const int i = blockIdx.x * 256 + threadIdx.x;
    if (i >= 6 * 6912) return;
    const int l = i / 6912, p = i % 6912;
    float v;
    if      (p < 768)  v = bq[l * 768 + p] * 0.125f;
    else if (p < 1536) v = bk[l * 768 + p - 768];
    else if (p < 2304) v = bv[l * 768 + p - 1536];
    else if (p < 3072) v = bo[l * 768 + p - 2304];
    else if (p < 6144) v = b1[(size_t)l * 3072 + p - 3072];
    else               v = b2[l * 768 + p - 6144];
    ba[i] = v;
}

// ---------------------------------------------------------------------------
// Per-layer weight converter: all 6 matrices -> transposed bf16 arena.
// ---------------------------------------------------------------------------
static constexpr size_t OFF_WO = (size_t)2304 * 768;
static constexpr size_t OFF_W1 = OFF_WO + (size_t)768 * 768;
static constexpr size_t OFF_W2 = OFF_W1 + (size_t)3072 * 768;
static constexpr size_t WARENA_E = OFF_W2 + (size_t)768 * 3072;

__global__ __launch_bounds__(256) void cvt_all(
    const float* __restrict__ Wq, const float* __restrict__ Wk,
    const float* __restrict__ Wv, const float* __restrict__ Wo,
    const float* __restrict__ W1, const float* __restrict__ W2,
    u16* __restrict__ wa)
{
    __shared__ float T[64][68];
    const int t = blockIdx.x;
    const float* S; u16* Dp; int Nsrc, Kdst, srow0, scol0; float sc = 1.f;
    if (t < 432) {
        const int ni = t % 36, ki = t / 36;
        const int ng = ni * 64;
        const int sel = ng / 768;
        scol0 = ng % 768; srow0 = ki * 64;
        S = (sel == 0) ? Wq : (sel == 1) ? Wk : Wv;
        if (sel == 0) sc = 0.125f;
        Nsrc = 768; Kdst = 768;
        Dp = wa + (size_t)ng * 768 + srow0;
    } else if (t < 576) {
        const int tt = t - 432; const int ni = tt % 12, ki = tt / 12;
        scol0 = ni * 64; srow0 = ki * 64;
        S = Wo; Nsrc = 768; Kdst = 768;
        Dp = wa + OFF_WO + (size_t)(ni * 64) * 768 + srow0;
    } else if (t < 1152) {
        const int tt = t - 576; const int ni = tt % 48, ki = tt / 48;
        scol0 = ni * 64; srow0 = ki * 64;
        S = W1; Nsrc = 3072; Kdst = 768;
        Dp = wa + OFF_W1 + (size_t)(ni * 64) * 768 + srow0;
    } else {
        const int tt = t - 1152; const int ni = tt % 12, ki = tt / 12;
        scol0 = ni * 64; srow0 = ki * 64;
        S = W2; Nsrc = 768; Kdst = 3072;
        Dp = wa + OFF_W2 + (size_t)(ni * 64) * 3072 + srow0;
    }
    const int tid = threadIdx.x;
#pragma unroll
    for (int i = 0; i < 4; ++i) {
        const int idx = tid + (i << 8);
        const int kr = idx >> 4;
        const int nc = (idx & 15) << 2;
        const float4 v = *(const float4*)(S + (size_t)(srow0 + kr) * Nsrc + scol0 + nc);
        T[kr][nc] = v.x; T[kr][nc + 1] = v.y; T[kr][nc + 2] = v.z; T[kr][nc + 3] = v.w;
    }
    __syncthreads();
#pragma unroll
    for (int i = 0; i < 4; ++i) {
        const int idx = tid + (i << 8);
        const int nr = idx >> 4;
        const int kc = (idx & 15) << 2;
        ushort4 o;
        o.x = f2bf(T[kc][nr] * sc);     o.y = f2bf(T[kc + 1][nr] * sc);
        o.z = f2bf(T[kc + 2][nr] * sc); o.w = f2bf(T[kc + 3][nr] * sc);
        *(ushort4*)(Dp + (size_t)nr * Kdst + kc) = o;
    }
}

// ---------------------------------------------------------------------------
// bf16 MFMA GEMM, 128x128 tile, BK=32, 2-phase counted-vmcnt pipeline,
// XCD-aware bijective block swizzle (T1).
// C[M,N] = A[M,K] @ Bt[N,K]^T + bias. mode: 0=f32 out, 1=bf16, 2=bf16+ReLU
// ---------------------------------------------------------------------------
__global__ __launch_bounds__(256) void gemm_bf16(
    const u16* __restrict__ A, const u16* __restrict__ Bt,
    const float* __restrict__ bias, void* __restrict__ Cv,
    int M, int N, int K, int mode)
{
    __shared__ u16 As[2][4096];
    __shared__ u16 Bs[2][4096];
    const int tid = threadIdx.x;
    const int l = tid & 63;
    const int lo = l & 15, hi = l >> 4;
    const int w = tid >> 6, wr = w >> 1, wc = w & 1;

    // XCD swizzle: 8 consecutive row-tiles + all col-tiles per XCD chunk
    int brow = blockIdx.x, bcol = blockIdx.y;
    const int gx = gridDim.x;
    if ((gx & 7) == 0) {
        const int id = blockIdx.y * gx + blockIdx.x;
        const int xcd = id & 7, idx = id >> 3;
        const int rpx = gx >> 3;
        brow = xcd * rpx + (idx % rpx);
        bcol = idx / rpx;
    }
    const size_t row0 = (size_t)brow * 128;
    const size_t col0 = (size_t)bcol * 128;

    const int c0 = tid, c1 = tid + 256;
    const int r0 = c0 >> 2, g0 = (c0 & 3) ^ ((r0 >> 1) & 3);
    const int r1 = c1 >> 2, g1 = (c1 & 3) ^ ((r1 >> 1) & 3);
    const u16* a0 = A  + (row0 + r0) * K + g0 * 8;
    const u16* a1 = A  + (row0 + r1) * K + g1 * 8;
    const u16* b0 = Bt + (col0 + r0) * K + g0 * 8;
    const u16* b1 = Bt + (col0 + r1) * K + g1 * 8;

    f32x4 acc[4][4];
#pragma unroll
    for (int i = 0; i < 4; ++i)
#pragma unroll
        for (int j = 0; j < 4; ++j)
#pragma unroll
            for (int r = 0; r < 4; ++r) acc[i][j][r] = 0.f;

    int aoff[4], boff[4];
#pragma unroll
    for (int i = 0; i < 4; ++i) {
        const int ra = wr * 64 + i * 16 + lo;
        aoff[i] = ra * 32 + ((hi ^ ((ra >> 1) & 3)) << 3);
        const int rb = wc * 64 + i * 16 + lo;
        boff[i] = rb * 32 + ((hi ^ ((rb >> 1) & 3)) << 3);
    }

    const int NT = K >> 5;
    gload16(a0, As[0] + c0 * 8);
    gload16(a1, As[0] + c1 * 8);
    gload16(b0, Bs[0] + c0 * 8);
    gload16(b1, Bs[0] + c1 * 8);

    int cur = 0;
    for (int t = 0; t < NT; ++t) {
        if (t + 1 < NT) {
            const int k0 = (t + 1) << 5;
            const int nb = cur ^ 1;
            gload16(a0 + k0, As[nb] + c0 * 8);
            gload16(a1 + k0, As[nb] + c1 * 8);
            gload16(b0 + k0, Bs[nb] + c0 * 8);
            gload16(b1 + k0, Bs[nb] + c1 * 8);
            asm volatile("s_waitcnt vmcnt(4)" ::: "memory");
        } else {
            asm volatile("s_waitcnt vmcnt(0)" ::: "memory");
        }
        __builtin_amdgcn_s_barrier();
        bf16x8 af[4], bfr[4];
#pragma unroll
        for (int i = 0; i < 4; ++i) af[i]  = *(const bf16x8*)&As[cur][aoff[i]];
#pragma unroll
        for (int j = 0; j < 4; ++j) bfr[j] = *(const bf16x8*)&Bs[cur][boff[j]];
#pragma unroll
        for (int i = 0; i < 4; ++i)
#pragma unroll
            for (int j = 0; j < 4; ++j)
                acc[i][j] = __builtin_amdgcn_mfma_f32_16x16x32_bf16(
                    af[i], bfr[j], acc[i][j], 0, 0, 0);
        asm volatile("s_waitcnt lgkmcnt(0)" ::: "memory");
        __builtin_amdgcn_sched_barrier(0);
        __builtin_amdgcn_s_barrier();
        cur ^= 1;
    }

#pragma unroll
    for (int i = 0; i < 4; ++i) {
        const size_t rbase = row0 + wr * 64 + i * 16 + hi * 4;
#pragma unroll
        for (int j = 0; j < 4; ++j) {
            const size_t c = col0 + wc * 64 + j * 16 + lo;
            const float bs = bias[c];
#pragma unroll
            for (int r = 0; r < 4; ++r) {
                float v = acc[i][j][r] + bs;
                if (mode == 2) v = fmaxf(v, 0.f);
                const size_t off = (rbase + r) * (size_t)N + c;
                if (mode == 0) ((float*)Cv)[off] = v;
                else           ((u16*)Cv)[off]  = f2bf(v);
            }
        }
    }
}

// ---------------------------------------------------------------------------
// MFMA flash attention v3 — swapped QK^T, in-register softmax,
// double-buffered K/V with async prefetch (K via global_load_lds,
// V via reg-staged scatter issued before softmax).
// Grid (S/64, H, B); 4 waves x 16 q-rows.
// ---------------------------------------------------------------------------
__device__ __forceinline__ void vscatter(u16* VtB, uint4 v4, int key, int sx)
{
    union { uint4 u; u16 s[8]; } vv; vv.u = v4;
    const int e0 = sx << 3;
#pragma unroll
    for (int e = 0; e < 8; ++e) {
        const int d = e0 + e;
        const int svz = (d & 7) ^ ((d >> 3) & 7);
        VtB[d * 64 + (key ^ (svz << 3))] = vv.s[e];
    }
}

__global__ __launch_bounds__(256) void attn_mfma(
    const u16* __restrict__ QKV, const u64* __restrict__ mbits,
    u16* __restrict__ O)
{
    __shared__ u16 Ks[2][4096];       // [key][64dk], slot-swizzled
    __shared__ u16 Vt[2][4096];       // [dk][64key], slot-swizzled
    __shared__ u16 PT[4][1024];       // per wave: [q=16][key=64], swizzled

    const int tid = threadIdx.x, l = tid & 63, w = tid >> 6;
    const int lo = l & 15, hi = l >> 4;
    const int h = blockIdx.y, b = blockIdx.z;
    const int q0 = blockIdx.x << 6;

    bf16x8 qf0, qf1;
    {
        const u16* qp = QKV + ((size_t)(b * kS + q0 + w * 16 + lo)) * kQW
                            + h * 64 + hi * 8;
        qf0 = *(const bf16x8*)qp;
        qf1 = *(const bf16x8*)(qp + 32);
    }

    const int ga = tid, gb = tid + 256;
    const int keyA = ga >> 3, sxA = ga & 7, EA = sxA ^ (keyA & 7);
    const int keyB = gb >> 3, sxB = gb & 7, EB = sxB ^ (keyB & 7);
    const u16* Kbase = QKV + 768  + (size_t)(b * kS) * kQW + h * 64;
    const u16* Vbase = QKV + 1536 + (size_t)(b * kS) * kQW + h * 64;

    f32x4 accO[4];
#pragma unroll
    for (int n = 0; n < 4; ++n)
#pragma unroll
        for (int r = 0; r < 4; ++r) accO[n][r] = 0.f;
    float m = -3.0e38f, lsum = 0.f;

    const int ksw = (lo & 7) << 3;
    constexpr int NT = kS / 64;

    // prologue: stage tile 0
    {
        gload16(Kbase + (size_t)keyA * kQW + EA * 8, Ks[0] + ga * 8);
        gload16(Kbase + (size_t)keyB * kQW + EB * 8, Ks[0] + gb * 8);
        const uint4 vA = *(const uint4*)(Vbase + (size_t)keyA * kQW + sxA * 8);
        const uint4 vB = *(const uint4*)(Vbase + (size_t)keyB * kQW + sxB * 8);
        vscatter(Vt[0], vA, keyA, sxA);
        vscatter(Vt[0], vB, keyB, sxB);
    }

    int cur = 0;
    for (int kt = 0; kt < NT; ++kt) {
        asm volatile("s_waitcnt vmcnt(0)" ::: "memory");
        __syncthreads();

        // prefetch next tile: K -> LDS (other buffer), V -> regs
        uint4 vA, vB;
        const bool pf = (kt + 1 < NT);
        if (pf) {
            const size_t tb = (size_t)((kt + 1) << 6) * kQW;
            const int nb = cur ^ 1;
            gload16(Kbase + tb + (size_t)keyA * kQW + EA * 8, Ks[nb] + ga * 8);
            gload16(Kbase + tb + (size_t)keyB * kQW + EB * 8, Ks[nb] + gb * 8);
            vA = *(const uint4*)(Vbase + tb + (size_t)keyA * kQW + sxA * 8);
            vB = *(const uint4*)(Vbase + tb + (size_t)keyB * kQW + sxB * 8);
        }

        // ---- scores S^T: lane: q=lo, keys j*16+hi*4+r ----
        f32x4 st[4];
        __builtin_amdgcn_s_setprio(1);
#pragma unroll
        for (int j = 0; j < 4; ++j) {
#pragma unroll
            for (int r = 0; r < 4; ++r) st[j][r] = 0.f;
            const int kb = (j * 16 + lo) * 64;
            const bf16x8 k0 = *(const bf16x8*)&Ks[cur][kb + ((hi * 8)      ^ ksw)];
            const bf16x8 k1 = *(const bf16x8*)&Ks[cur][kb + ((hi * 8 + 32) ^ ksw)];
            st[j] = __builtin_amdgcn_mfma_f32_16x16x32_bf16(k0, qf0, st[j], 0, 0, 0);
            st[j] = __builtin_amdgcn_mfma_f32_16x16x32_bf16(k1, qf1, st[j], 0, 0, 0);
        }
        __builtin_amdgcn_s_setprio(0);

        // ---- online softmax, row = q = lo ----
        float rmax = st[0][0];
#pragma unroll
        for (int j = 0; j < 4; ++j)
#pragma unroll
            for (int r = 0; r < 4; ++r) rmax = fmaxf(rmax, st[j][r]);
        rmax = fmaxf(rmax, __shfl_xor(rmax, 16));
        rmax = fmaxf(rmax, __shfl_xor(rmax, 32));

        const bool skip = __all(rmax <= m + 8.0f);
        if (!skip) {
            const float mn = fmaxf(m, rmax);
            const float corr = __expf(m - mn);
            m = mn;
            lsum *= corr;
            float c2[4];
#pragma unroll
            for (int r = 0; r < 4; ++r) c2[r] = __shfl(corr, hi * 4 + r);
#pragma unroll
            for (int n = 0; n < 4; ++n)
#pragma unroll
                for (int r = 0; r < 4; ++r) accO[n][r] *= c2[r];
        }

#pragma unroll
        for (int j = 0; j < 4; ++j)
#pragma unroll
            for (int r = 0; r < 4; ++r) st[j][r] = __expf(st[j][r] - m);

        const u64 mb = mbits[b * 32 + kt];
        if (mb != ~0ull) {
#pragma unroll
            for (int j = 0; j < 4; ++j)
#pragma unroll
                for (int r = 0; r < 4; ++r)
                    if (!((mb >> (j * 16 + hi * 4 + r)) & 1)) st[j][r] = 0.f;
        }

        float ts = 0.f;
#pragma unroll
        for (int j = 0; j < 4; ++j)
#pragma unroll
            for (int r = 0; r < 4; ++r) ts += st[j][r];
        ts += __shfl_xor(ts, 16);
        ts += __shfl_xor(ts, 32);
        lsum += ts;

        // ---- V prefetch lands in next buffer (waits its vmcnt only) ----
        if (pf) {
            vscatter(Vt[cur ^ 1], vA, keyA, sxA);
            vscatter(Vt[cur ^ 1], vB, keyB, sxB);
        }

        // ---- pack P -> PT (wave-private, swizzled) ----
        u16* pw = PT[w];
#pragma unroll
        for (int j = 0; j < 4; ++j) {
            uint2 pk;
            pk.x = cvtpk(st[j][0], st[j][1]);
            pk.y = cvtpk(st[j][2], st[j][3]);
            *(uint2*)&pw[lo * 64 + (((j << 4) + (hi << 2)) ^ ksw)] = pk;
        }
        const bf16x8 pa0 = *(const bf16x8*)&pw[lo * 64 + ((hi * 8)      ^ ksw)];
        const bf16x8 pa1 = *(const bf16x8*)&pw[lo * 64 + ((hi * 8 + 32) ^ ksw)];

        // ---- PV ----
        __builtin_amdgcn_s_setprio(1);
#pragma unroll
        for (int n = 0; n < 4; ++n) {
            const int d = n * 16 + lo;
            const int svz = ((d & 7) ^ ((d >> 3) & 7)) << 3;
            const bf16x8 v0 = *(const bf16x8*)&Vt[cur][d * 64 + ((hi * 8)      ^ svz)];
            const bf16x8 v1 = *(const bf16x8*)&Vt[cur][d * 64 + ((hi * 8 + 32) ^ svz)];
            accO[n] = __builtin_amdgcn_mfma_f32_16x16x32_bf16(pa0, v0, accO[n], 0, 0, 0);
            accO[n] = __builtin_amdgcn_mfma_f32_16x16x32_bf16(pa1, v1, accO[n], 0, 0, 0);
        }
        __builtin_amdgcn_s_setprio(0);
        cur ^= 1;
    }

    float linv[4];
#pragma unroll
    for (int r = 0; r < 4; ++r) linv[r] = 1.f / __shfl(lsum, hi * 4 + r);
#pragma unroll
    for (int n = 0; n < 4; ++n)
#pragma unroll
        for (int r = 0; r < 4; ++r)
            O[((size_t)(b * kS + q0 + w * 16 + hi * 4 + r)) * kD
              + h * 64 + n * 16 + lo] = f2bf(accO[n][r] * linv[r]);
}

// ---------------------------------------------------------------------------
// out = LayerNorm(a + r); wave-per-row, float4; dual f32 + optional bf16
// ---------------------------------------------------------------------------
__global__ __launch_bounds__(256) void add_ln(
    const float* __restrict__ a, const float* __restrict__ r,
    const float* __restrict__ g, const float* __restrict__ bt,
    float* __restrict__ out, u16* __restrict__ outb)
{
    const int lane = threadIdx.x & 63;
    const size_t row = (size_t)blockIdx.x * 4 + (threadIdx.x >> 6);
    const float4* a4 = (const float4*)(a + row * kD);
    const float4* r4 = (const float4*)(r + row * kD);
    float4 v[3];
    float s = 0.f;
#pragma unroll
    for (int j = 0; j < 3; ++j) {
        const float4 av = a4[j * 64 + lane];
        const float4 rv = r4[j * 64 + lane];
        v[j].x = av.x + rv.x; v[j].y = av.y + rv.y;
        v[j].z = av.z + rv.z; v[j].w = av.w + rv.w;
        s += v[j].x + v[j].y + v[j].z + v[j].w;
    }
#pragma unroll
    for (int off = 32; off; off >>= 1) s += __shfl_xor(s, off);
    const float mu = s * (1.f / 768.f);
    float vs = 0.f;
#pragma unroll
    for (int j = 0; j < 3; ++j) {
        float t0 = v[j].x - mu, t1 = v[j].y - mu, t2 = v[j].z - mu, t3 = v[j].w - mu;
        vs = fmaf(t0, t0, fmaf(t1, t1, fmaf(t2, t2, fmaf(t3, t3, vs))));
    }
#pragma unroll
    for (int off = 32; off; off >>= 1) vs += __shfl_xor(vs, off);
    const float rstd = rsqrtf(vs * (1.f / 768.f) + 1e-5f);
    const float4* g4 = (const float4*)g;
    const float4* b4 = (const float4*)bt;
#pragma unroll
    for (int j = 0; j < 3; ++j) {
        const float4 gv = g4[j * 64 + lane];
        const float4 bv = b4[j * 64 + lane];
        float4 o;
        o.x = (v[j].x - mu) * rstd * gv.x + bv.x;
        o.y = (v[j].y - mu) * rstd * gv.y + bv.y;
        o.z = (v[j].z - mu) * rstd * gv.z + bv.z;
        o.w = (v[j].w - mu) * rstd * gv.w + bv.w;
        ((float4*)(out + row * kD))[j * 64 + lane] = o;
        if (outb) {
            ushort4 ob4;
            ob4.x = f2bf(o.x); ob4.y = f2bf(o.y);
            ob4.z = f2bf(o.z); ob4.w = f2bf(o.w);
            ((ushort4*)(outb + row * kD))[j * 64 + lane] = ob4;
        }
    }
}

// ---------------------------------------------------------------------------
// mean over s: 2-stage deterministic reduction
// stage1: grid (64, B): block (c,b) sums s in [c*32, c*32+32) for all 768 d
// stage2: grid (3, B): sums the 64 partials
// ---------------------------------------------------------------------------
__global__ __launch_bounds__(256) void mean_part(
    const float* __restrict__ x, float* __restrict__ mred)
{
    const int c = blockIdx.x, b = blockIdx.y;
    const int tid = threadIdx.x;
    const float* base = x + ((size_t)b * kS + c * 32) * kD;
#pragma unroll
    for (int j = 0; j < 3; ++j) {
        const int d = tid + (j << 8);
        float s = 0.f;
#pragma unroll 8
        for (int t = 0; t < 32; ++t) s += base[(size_t)t * kD + d];
        mred[((size_t)b * 64 + c) * kD + d] = s;
    }
}

__global__ __launch_bounds__(256) void mean_fin(
    const float* __restrict__ mred, float* __restrict__ out)
{
    const int d = blockIdx.x * 256 + threadIdx.x;
    const int b = blockIdx.y;
    float s = 0.f;
#pragma unroll
    for (int c = 0; c < 64; ++c) s += mred[((size_t)b * 64 + c) * kD + d];
    out[b * kD + d] = s * (1.f / 2048.f);
}

// naive mean (fallback path only)
__global__ __launch_bounds__(256) void mean_s(
    const float* __restrict__ x, float* __restrict__ out)
{
    const int d = blockIdx.x * 256 + threadIdx.x;
    const int b = blockIdx.y;
    float s = 0.f;
    for (int t = 0; t < kS; ++t) s += x[((size_t)b * kS + t) * kD + d];
    out[b * kD + d] = s * (1.f / 2048.f);
}

// ---------------------------------------------------------------------------
// FALLBACK f32 kernels (used only if ws too small)
// ---------------------------------------------------------------------------
__global__ __launch_bounds__(256) void gemm_f32(
    const float* __restrict__ A, const float* __restrict__ W,
    const float* __restrict__ bias, float* __restrict__ C,
    int M, int N, int K, int relu)
{
    __shared__ float As[16][68];
    __shared__ float Bs[16][68];
    const int tid = threadIdx.x;
    const int row0 = blockIdx.x << 6;
    const int col0 = blockIdx.y << 6;
    const int tx = tid & 15, ty = tid >> 4;
    const int ar = tid >> 2;
    const int ak = (tid & 3) << 2;
    const int bk = tid >> 4;
    const int bc = (tid & 15) << 2;
    float acc[4][4] = {};
    const float* Ap = A + (size_t)(row0 + ar) * K + ak;
    const float* Wp = W + (size_t)bk * N + col0 + bc;
    for (int k0 = 0; k0 < K; k0 += 16) {
        const float4 a4 = *(const float4*)(Ap + k0);
        const float4 b4 = *(const float4*)(Wp + (size_t)k0 * N);
        __syncthreads();
        As[ak + 0][ar] = a4.x; As[ak + 1][ar] = a4.y;
        As[ak + 2][ar] = a4.z; As[ak + 3][ar] = a4.w;
        *(float4*)&Bs[bk][bc] = b4;
        __syncthreads();
#pragma unroll
        for (int kk = 0; kk < 16; ++kk) {
            const float4 av = *(const float4*)&As[kk][ty << 2];
            const float4 bv = *(const float4*)&Bs[kk][tx << 2];
            const float aa[4] = {av.x, av.y, av.z, av.w};
            const float bb[4] = {bv.x, bv.y, bv.z, bv.w};
#pragma unroll
            for (int i = 0; i < 4; ++i)
#pragma unroll
                for (int j = 0; j < 4; ++j)
                    acc[i][j] = fmaf(aa[i], bb[j], acc[i][j]);
        }
    }
#pragma unroll
    for (int i = 0; i < 4; ++i) {
        const int row = row0 + (ty << 2) + i;
#pragma unroll
        for (int j = 0; j < 4; ++j) {
            const int col = col0 + (tx << 2) + j;
            float v = acc[i][j] + bias[col];
            if (relu) v = fmaxf(v, 0.f);
            C[(size_t)row * N + col] = v;
        }
    }
}

__global__ __launch_bounds__(256) void attn_fused(
    const float* __restrict__ Q, const float* __restrict__ Km,
    const float* __restrict__ Vm, const int* __restrict__ ids,
    float* __restrict__ O)
{
    __shared__ float Ksf[64 * 64];
    __shared__ float Vtf[64 * 64];
    __shared__ float Qs[16][64];
    __shared__ float Psf[4][4][64];
    const int tid = threadIdx.x;
    const int w = tid >> 6;
    const int lane = tid & 63;
    const int h = blockIdx.y, b = blockIdx.z;
    const int qrow0 = blockIdx.x << 4;
    {
        const int r = tid >> 4;
        const int c4 = tid & 15;
        const float4 q4 = *(const float4*)(
            Q + ((size_t)(b * kS + qrow0 + r)) * kD + h * 64 + (c4 << 2));
        Qs[r][(c4 << 2) + 0] = q4.x * 0.125f;
        Qs[r][(c4 << 2) + 1] = q4.y * 0.125f;
        Qs[r][(c4 << 2) + 2] = q4.z * 0.125f;
        Qs[r][(c4 << 2) + 3] = q4.w * 0.125f;
    }
    float m[4], lsum[4], o[4];
#pragma unroll
    for (int r = 0; r < 4; ++r) { m[r] = -3.0e38f; lsum[r] = 0.f; o[r] = 0.f; }
    for (int kt = 0; kt < kS / 64; ++kt) {
        __syncthreads();
#pragma unroll
        for (int i = 0; i < 4; ++i) {
            const int lin = tid + (i << 8);
            const int row = lin >> 4;
            const int s4 = lin & 15;
            const size_t gro = ((size_t)(b * kS + (kt << 6) + row)) * kD + h * 64 + (s4 << 2);
            const float4 k4 = *(const float4*)(Km + gro);
            ((float4*)Ksf)[(row << 4) + (s4 ^ (row & 7))] = k4;
            const float4 v4 = *(const float4*)(Vm + gro);
            const int ksl = row >> 2, ke = row & 3;
            const int d0 = s4 << 2;
            Vtf[(d0 + 0) * 64 + ((ksl ^ ((d0 + 0) & 7)) << 2) + ke] = v4.x;
            Vtf[(d0 + 1) * 64 + ((ksl ^ ((d0 + 1) & 7)) << 2) + ke] = v4.y;
            Vtf[(d0 + 2) * 64 + ((ksl ^ ((d0 + 2) & 7)) << 2) + ke] = v4.z;
            Vtf[(d0 + 3) * 64 + ((ksl ^ ((d0 + 3) & 7)) << 2) + ke] = v4.w;
        }
        __syncthreads();
        const bool masked = (ids[(size_t)b * kS + (kt << 6) + lane] == 1);
        float scr[4] = {0.f, 0.f, 0.f, 0.f};
#pragma unroll
        for (int i16 = 0; i16 < 16; ++i16) {
            const float4 kv = ((const float4*)Ksf)[(lane << 4) + (i16 ^ (lane & 7))];
#pragma unroll
            for (int r = 0; r < 4; ++r) {
                const float4 qv = *(const float4*)&Qs[(w << 2) + r][i16 << 2];
                scr[r] = fmaf(kv.x, qv.x, fmaf(kv.y, qv.y,
                          fmaf(kv.z, qv.z, fmaf(kv.w, qv.w, scr[r]))));
            }
        }
#pragma unroll
        for (int r = 0; r < 4; ++r) {
            float sm = masked ? -3.0e38f : scr[r];
#pragma unroll
            for (int off = 32; off; off >>= 1) sm = fmaxf(sm, __shfl_xor(sm, off));
            const float mn = fmaxf(m[r], sm);
            const float cr = __expf(m[r] - mn);
            const float pv = masked ? 0.f : __expf(scr[r] - mn);
            float ps = pv;
#pragma unroll
            for (int off = 32; off; off >>= 1) ps += __shfl_xor(ps, off);
            lsum[r] = lsum[r] * cr + ps;
            o[r] *= cr;
            m[r] = mn;
            Psf[w][r][lane] = pv;
        }
#pragma unroll
        for (int i16 = 0; i16 < 16; ++i16) {
            const float4 vv = ((const float4*)Vtf)[(lane << 4) + (i16 ^ (lane & 7))];
#pragma unroll
            for (int r = 0; r < 4; ++r) {
                const float4 pv = *(const float4*)&Psf[w][r][i16 << 2];
                o[r] = fmaf(pv.x, vv.x, fmaf(pv.y, vv.y,
                        fmaf(pv.z, vv.z, fmaf(pv.w, vv.w, o[r]))));
            }
        }
    }
#pragma unroll
    for (int r = 0; r < 4; ++r)
        O[((size_t)(b * kS + qrow0 + (w << 2) + r)) * kD + h * 64 + lane] =
            o[r] / lsum[r];
}

// ---------------------------------------------------------------------------
// Host orchestration
// ---------------------------------------------------------------------------
extern "C" void kernel_launch(void* const* d_in, const int* in_sizes, int n_in,
                              void* d_out, int out_size, void* d_ws, size_t ws_size,
                              hipStream_t stream)
{
    const int*   ids   = (const int*)  d_in[0];
    const float* emb   = (const float*)d_in[1];
    const float* Wq    = (const float*)d_in[2];
    const float* bq    = (const float*)d_in[3];
    const float* Wk    = (const float*)d_in[4];
    const float* bk    = (const float*)d_in[5];
    const float* Wv    = (const float*)d_in[6];
    const float* bv    = (const float*)d_in[7];
    const float* Wo    = (const float*)d_in[8];
    const float* bo    = (const float*)d_in[9];
    const float* W1    = (const float*)d_in[10];
    const float* b1    = (const float*)d_in[11];
    const float* W2    = (const float*)d_in[12];
    const float* b2    = (const float*)d_in[13];
    const float* gamma = (const float*)d_in[14];
    const float* beta  = (const float*)d_in[15];
    float* out = (float*)d_out;

    const size_t BUFE = (size_t)kB * kS * kD;          // 6,291,456
    const size_t WDD  = (size_t)kD * kD;
    const size_t WDF  = (size_t)kD * kF;
    const size_t HIDE = (size_t)kB * kS * kF;          // 25,165,824 (hidden/qkv scratch)
    const int NTOK = kB * kS;                          // 8192

    const size_t NEED = BUFE * 4 * 2                   // xb, ob (f32)
                      + BUFE * 2                       // abf
                      + HIDE * 2                       // shared qkv/hidden scratch
                      + WARENA_E * 2                   // weight arena
                      + (size_t)6 * 6912 * 4           // bias arena
                      + 128 * 8                        // mask bits
                      + (size_t)kB * 64 * kD * 4;      // mean partials

    if (ws_size >= NEED) {
        float* xb  = (float*)d_ws;
        float* ob  = xb + BUFE;
        u16*   abf = (u16*)(ob + BUFE);
        u16*   sc  = abf + BUFE;                       // qkv AND ffn-hidden
        u16*   wa  = sc + HIDE;
        float* ba  = (float*)(wa + WARENA_E);
        u64*   mbt = (u64*)(ba + 6 * 6912);
        float* mrd = (float*)(mbt + 128);

        embed_pe<<<NTOK, 256, 0, stream>>>(ids, emb, xb, abf);
        mk_maskbits<<<kB * kS / 64, 64, 0, stream>>>(ids, mbt);
        bias_build<<<(6 * 6912 + 255) / 256, 256, 0, stream>>>(
            bq, bk, bv, bo, b1, b2, ba);

        for (int l = 0; l < kL; ++l) {
            const size_t oDD = (size_t)l * WDD;
            const size_t oDF = (size_t)l * WDF;
            const float* bl = ba + (size_t)l * 6912;
            const float* gl  = gamma + (size_t)l * kD;
            const float* btl = beta  + (size_t)l * kD;

            cvt_all<<<1728, 256, 0, stream>>>(
                Wq + oDD, Wk + oDD, Wv + oDD, Wo + oDD, W1 + oDF, W2 + oDF, wa);

            // fused QKV projection (Q pre-scaled 1/8) -> sc
            gemm_bf16<<<dim3(64, 18), 256, 0, stream>>>(
                abf, wa, bl, sc, NTOK, kQW, kD, 1);

            attn_mfma<<<dim3(kS / 64, kH, kB), 256, 0, stream>>>(
                sc, mbt, abf);                         // attn out -> abf

            gemm_bf16<<<dim3(64, 6), 256, 0, stream>>>(
                abf, wa + OFF_WO, bl + 2304, ob, NTOK, kD, kD, 0);

            // x1 = LN(x + o): f32 -> ob (in place), bf16 -> abf
            add_ln<<<NTOK / 4, 256, 0, stream>>>(xb, ob, gl, btl, ob, abf);

            // FFN full-width; hidden -> sc
            gemm_bf16<<<dim3(64, 24), 256, 0, stream>>>(
                abf, wa + OFF_W1, bl + 3072, sc, NTOK, kF, kD, 2);
            gemm_bf16<<<dim3(64, 6), 256, 0, stream>>>(
                sc, wa + OFF_W2, bl + 6144, xb, NTOK, kD, kF, 0);

            // x = LN(x1 + ffn): f32 -> xb, bf16 -> abf
            add_ln<<<NTOK / 4, 256, 0, stream>>>(ob, xb, gl, btl, xb, abf);
        }

        mean_part<<<dim3(64, kB), 256, 0, stream>>>(xb, mrd);
        mean_fin<<<dim3(kD / 256, kB), 256, 0, stream>>>(mrd, out);
        return;
    }

    // -------- fallback f32 path --------
    if (ws_size < 5 * BUFE * sizeof(float)) return;
    float* xb = (float*)d_ws;
    float* kb = xb + BUFE;
    float* qb = kb + BUFE;
    float* vb = qb + BUFE;
    float* obf = vb + BUFE;
    float* hb = qb;

    embed_pe<<<NTOK, 256, 0, stream>>>(ids, emb, xb, nullptr);
    for (int l = 0; l < kL; ++l) {
        const size_t oDD = (size_t)l * WDD;
        const size_t oDF = (size_t)l * WDF;
        gemm_f32<<<dim3(NTOK / 64, kD / 64), 256, 0, stream>>>(
            xb, Wq + oDD, bq + (size_t)l * kD, qb, NTOK, kD, kD, 0);
        gemm_f32<<<dim3(NTOK / 64, kD / 64), 256, 0, stream>>>(
            xb, Wk + oDD, bk + (size_t)l * kD, kb, NTOK, kD, kD, 0);
        gemm_f32<<<dim3(NTOK / 64, kD / 64), 256, 0, stream>>>(
            xb, Wv + oDD, bv + (size_t)l * kD, vb, NTOK, kD, kD, 0);
        attn_fused<<<dim3(kS / 16, kH, kB), 256, 0, stream>>>(qb, kb, vb, ids, obf);
        gemm_f32<<<dim3(NTOK / 64, kD / 64), 256, 0, stream>>>(
            obf, Wo + oDD, bo + (size_t)l * kD, qb, NTOK, kD, kD, 0);
        add_ln<<<NTOK / 4, 256, 0, stream>>>(xb, qb,
            gamma + (size_t)l * kD, beta + (size_t)l * kD, kb, nullptr);
        for (int c = 0; c < 2; ++c) {
            const size_t ro = (size_t)c * 4096;
            gemm_f32<<<dim3(4096 / 64, kF / 64), 256, 0, stream>>>(
                kb + ro * kD, W1 + oDF, b1 + (size_t)l * kF, hb, 4096, kF, kD, 1);
            gemm_f32<<<dim3(4096 / 64, kD / 64), 256, 0, stream>>>(
                hb, W2 + oDF, b2 + (size_t)l * kD, obf + ro * kD, 4096, kD, kF, 0);
        }
        add_ln<<<NTOK / 4, 256, 0, stream>>>(kb, obf,
            gamma + (size_t)l * kD, beta + (size_t)l * kD, xb, nullptr);
    }
    mean_s<<<dim3(kD / 256, kB), 256, 0, stream>>>(xb, out);
}